// Round 9
// baseline (1199.483 us; speedup 1.0000x reference)
//
#include <hip/hip_runtime.h>

typedef unsigned char  u8;
typedef unsigned short u16;
typedef unsigned int   u32;
typedef unsigned long long u64;
typedef __attribute__((ext_vector_type(8))) short s8v;   // 8 x bf16 bits (4 VGPRs)
typedef __attribute__((ext_vector_type(4))) float f4v;   // MFMA accumulator
typedef __attribute__((ext_vector_type(4))) int   i4v;   // 4 VGPRs (generic 16B)
typedef __attribute__((ext_vector_type(8))) int   i8v;   // 8 VGPRs (fp8 MFMA operand)
typedef __attribute__((ext_vector_type(2))) unsigned int u32x2;

#define B_SZ  64
#define T_LEN 512
#define U_DIM 256
#define E_DIM 300
#define EP    320          // E padded to multiple of 32
#define G3    768          // 3*U
#define NTOT  1536         // both directions concatenated
#define C_DIM 20
#define BT    (B_SZ*T_LEN)

// log2(e) scales folded into weights/biases so gates use native exp2
#define L2E  1.44269504088896f
#define L2E2 2.88539008177793f

__device__ __forceinline__ float bf2f(u16 h){ return __uint_as_float(((u32)h)<<16); }
__device__ __forceinline__ u16 f2bf(float f){
  u32 u = __float_as_uint(f);
  u32 r = (u + 0x7FFFu + ((u>>16)&1u)) >> 16;   // RNE
  return (u16)r;
}

// f32 -> OCP e4m3fn, RNE, handles subnormals + 448 clamp (prep kernels only)
__device__ __forceinline__ u8 f2fp8(float f){
  u32 u = __float_as_uint(f);
  u32 s = (u>>24)&0x80u;
  u32 au = u & 0x7fffffffu;
  if(au < 0x3C800000u){                       // |f| < 2^-6: subnormal range
    float m = rintf(__uint_as_float(au) * 512.f);   // 0..8 (RNE)
    return (u8)(s | (u32)(int)m);             // m==8 -> 0x08 == 2^-6 normal
  }
  int e = (int)(au>>23) - 127;
  u32 mant = au & 0x7fffffu;
  u32 lsb = (mant>>20)&1u;
  mant += 0x7FFFFu + lsb;                     // RNE to 3 mantissa bits
  if(mant >> 23){ mant = 0; e += 1; }
  if(e > 8 || (e==8 && ((mant>>20)&7u)==7u)) return (u8)(s | 0x7Eu);  // clamp 448
  return (u8)(s | ((u32)(e+7)<<3) | ((mant>>20)&7u));
}

// ------------- embedding gather f32 -> bf16, K-pad (300 -> 320, zeros) --------
__global__ void embed_pad(const int* __restrict__ x, const float* __restrict__ emb,
                          u16* __restrict__ e){
  int idx = blockIdx.x*256 + threadIdx.x;
  if(idx >= BT*EP) return;
  int row = idx / EP, col = idx - row*EP;
  u16 v = 0;
  if(col < E_DIM) v = f2bf(emb[(size_t)x[row]*E_DIM + col]);
  e[idx] = v;
}

// ------ transpose + concat two f32 [K,768] sources -> bf16 dst[N][Kp] ---------
// Gate-dependent log2e scale folded into the input-projection weights.
__global__ void transpose_cc(const float* __restrict__ A, const float* __restrict__ Bm,
                             u16* __restrict__ dst, int K, int Kp, int N){
  int idx = blockIdx.x*256 + threadIdx.x;
  if(idx >= N*Kp) return;
  int n = idx / Kp, k = idx - n*Kp;
  u16 v = 0;
  if(k < K){
    const float* s = (n < G3) ? A : Bm;
    int nn = (n < G3) ? n : n - G3;
    float sc = ((nn>>8)==2) ? L2E2 : L2E;
    v = f2bf(s[(size_t)k*G3 + nn] * sc);
  }
  dst[idx] = v;
}

// ------ recurrent kernel f32 [256][768] -> fp8 e4m3 transposed [768][256] -----
// Same gate-dependent log2e scale folded into the recurrent weights.
__global__ void transpose_fp8(const float* __restrict__ rk, u8* __restrict__ dst){
  int idx = blockIdx.x*256 + threadIdx.x;     // 768*256
  if(idx >= G3*U_DIM) return;
  int n = idx >> 8, k = idx & 255;
  float sc = ((n>>8)==2) ? L2E2 : L2E;
  dst[idx] = f2fp8(rk[(size_t)k*G3 + n] * sc);
}

// ------- GEMM: packed preacts for the M=4 scan -------------------------------
// xq layout (u16): [dir][t][b][g][lc16][ut16]; total 2*512*64*3*256 u16.
// Recurrent bias b[1] for gates z,r (g<2) is folded in here; biases carry the
// same log2e gate scale as the weights (preacts live in log2 domain).
__global__ __launch_bounds__(256) void gemm_bt(
    const u16* __restrict__ A, const u16* __restrict__ BT_, u16* __restrict__ Cq,
    int Kp, const float* __restrict__ biasA, const float* __restrict__ biasB)
{
  __shared__ u16 Al[128][40];   // +8 pad breaks bank collisions
  __shared__ u16 Bl[128][40];
  int tid = threadIdx.x;
  int w = tid>>6, l = tid&63, lc = l&15, quad = l>>4;
  int wm = w>>1, wn = w&1;
  int nb = blockIdx.x*128;
  int bg4 = blockIdx.y >> 4, tg = blockIdx.y & 15;
  int b0r = bg4*4, tb0 = tg*32;

  f4v acc[4][4];
  #pragma unroll
  for(int i=0;i<4;i++)
    #pragma unroll
    for(int j=0;j<4;j++) acc[i][j] = (f4v){0.f,0.f,0.f,0.f};

  int nk = Kp >> 5;
  for(int kt=0; kt<nk; kt++){
    __syncthreads();
    {
      int c0 = tid, c1 = tid + 256;
      int r0 = c0>>2, k80 = c0&3;
      int r1 = c1>>2, k81 = c1&3;
      size_t ga0 = ((size_t)(b0r + (r0&3))*T_LEN + tb0 + (r0>>2))*Kp;
      size_t ga1 = ((size_t)(b0r + (r1&3))*T_LEN + tb0 + (r1>>2))*Kp;
      *(s8v*)&Al[r0][k80*8] = *(const s8v*)(A + ga0 + kt*32 + k80*8);
      *(s8v*)&Al[r1][k81*8] = *(const s8v*)(A + ga1 + kt*32 + k81*8);
      *(s8v*)&Bl[r0][k80*8] = *(const s8v*)(BT_ + (size_t)(nb+r0)*Kp + kt*32 + k80*8);
      *(s8v*)&Bl[r1][k81*8] = *(const s8v*)(BT_ + (size_t)(nb+r1)*Kp + kt*32 + k81*8);
    }
    __syncthreads();
    s8v af[4], bf[4];
    #pragma unroll
    for(int i=0;i<4;i++) af[i] = *(const s8v*)&Al[wm*64 + i*16 + lc][quad*8];
    #pragma unroll
    for(int j=0;j<4;j++) bf[j] = *(const s8v*)&Bl[wn*64 + j*16 + lc][quad*8];
    #pragma unroll
    for(int i=0;i<4;i++)
      #pragma unroll
      for(int j=0;j<4;j++)
        acc[i][j] = __builtin_amdgcn_mfma_f32_16x16x32_bf16(af[i], bf[j], acc[i][j],0,0,0);
  }

  // packed epilogue -> xq[dir][t][b][g][lc][ut], one u64 (4 ut) per (i,r)
  int dirq = (nb >= G3) ? 1 : 0;
  int c7b  = nb - dirq*G3 + wn*64;      // col within dir, minus lc and j*16
  int g    = c7b >> 8;
  int ut0  = (c7b >> 4) & 15;
  const float* bb = dirq ? biasB : biasA;
  float gsc = (g < 2) ? L2E : L2E2;
  float bj[4];
  #pragma unroll
  for(int j=0;j<4;j++){
    int cc = c7b + j*16 + lc;
    bj[j] = (bb[cc] + ((g < 2) ? bb[G3 + cc] : 0.f)) * gsc;  // fold b[1] for z,r
  }
  #pragma unroll
  for(int i=0;i<4;i++){
    int t = tb0 + wm*16 + i*4 + quad;
    size_t base = ((((size_t)dirq*T_LEN + t)*B_SZ + b0r)*3 + g)*256 + lc*16 + ut0;
    #pragma unroll
    for(int r=0;r<4;r++){
      u16 p0 = f2bf(acc[i][0][r] + bj[0]);
      u16 p1 = f2bf(acc[i][1][r] + bj[1]);
      u16 p2 = f2bf(acc[i][2][r] + bj[2]);
      u16 p3 = f2bf(acc[i][3][r] + bj[3]);
      *(u64*)(Cq + base + (size_t)r*768) =
        (u64)p0 | ((u64)p1<<16) | ((u64)p2<<32) | ((u64)p3<<48);
    }
  }
}

// ---------------- GRU scan: fp8 K=128 MFMA, register-resident weights --------
// 32 blocks (dir x 16 batch-groups of 4) x 256 threads (4 waves, 1 wave/SIMD).
// Per wave: 192 N-cols (3 gates x 64 u) x K=256 fp8 -> 24 B-frags x 8 AGPRs =
// a0..a191. h exchanged per step via LDS as fp8 bytes; gate state in f32.
// 24 MFMAs/step/wave (12 N-tiles x 2 K-tiles of 16x16x128).
// xq preact loads pipelined one step ahead. Preacts/weights are pre-scaled by
// log2e (z,r) / 2*log2e (h) so gates use native exp2 (no mul before v_exp).

#define ACLB \
 "a0","a1","a2","a3","a4","a5","a6","a7","a8","a9","a10","a11","a12","a13","a14","a15", \
 "a16","a17","a18","a19","a20","a21","a22","a23","a24","a25","a26","a27","a28","a29","a30","a31", \
 "a32","a33","a34","a35","a36","a37","a38","a39","a40","a41","a42","a43","a44","a45","a46","a47", \
 "a48","a49","a50","a51","a52","a53","a54","a55","a56","a57","a58","a59","a60","a61","a62","a63", \
 "a64","a65","a66","a67","a68","a69","a70","a71","a72","a73","a74","a75","a76","a77","a78","a79", \
 "a80","a81","a82","a83","a84","a85","a86","a87","a88","a89","a90","a91","a92","a93","a94","a95", \
 "a96","a97","a98","a99","a100","a101","a102","a103","a104","a105","a106","a107","a108","a109","a110","a111", \
 "a112","a113","a114","a115","a116","a117","a118","a119","a120","a121","a122","a123","a124","a125","a126","a127", \
 "a128","a129","a130","a131","a132","a133","a134","a135","a136","a137","a138","a139","a140","a141","a142","a143", \
 "a144","a145","a146","a147","a148","a149","a150","a151","a152","a153","a154","a155","a156","a157","a158","a159", \
 "a160","a161","a162","a163","a164","a165","a166","a167","a168","a169","a170","a171","a172","a173","a174","a175", \
 "a176","a177","a178","a179","a180","a181","a182","a183","a184","a185","a186","a187","a188","a189","a190","a191"

#define AFENCE asm volatile("" ::: ACLB)

#define BINIT8(G,S,KT,A0,A1,A2,A3,A4,A5,A6,A7) { \
  const u8* p = rkd + ((size_t)((G)*256 + w*64 + (S)*16 + lc)<<8) + (KT)*128 + quad*32; \
  i4v t0 = *(const i4v*)p; \
  i4v t1 = *(const i4v*)(p+16); \
  asm volatile("v_accvgpr_write_b32 a" #A0 ", %0\n\t" \
               "v_accvgpr_write_b32 a" #A1 ", %1\n\t" \
               "v_accvgpr_write_b32 a" #A2 ", %2\n\t" \
               "v_accvgpr_write_b32 a" #A3 ", %3\n\t" \
               "v_accvgpr_write_b32 a" #A4 ", %4\n\t" \
               "v_accvgpr_write_b32 a" #A5 ", %5\n\t" \
               "v_accvgpr_write_b32 a" #A6 ", %6\n\t" \
               "v_accvgpr_write_b32 a" #A7 ", %7" \
               :: "v"(t0[0]),"v"(t0[1]),"v"(t0[2]),"v"(t0[3]), \
                  "v"(t1[0]),"v"(t1[1]),"v"(t1[2]),"v"(t1[3]) : ACLB); }

// fp8 K=128 MFMA, B from AGPR (cbsz/blgp default 0 = e4m3 both operands)
#define MFZ8(ACC,AF,AR) \
  asm("v_mfma_f32_16x16x128_f8f6f4 %0, %1, " AR ", 0" : "=&v"(ACC) : "v"(AF))
#define MFA8(ACC,AF,AR) \
  asm("v_mfma_f32_16x16x128_f8f6f4 %0, %1, " AR ", %0" : "+v"(ACC) : "v"(AF))

// MFMA->VALU hazard fence: orders all acc reads after 16 nop cycles
#define FENCE12 asm volatile("s_nop 7\n\ts_nop 7" \
  : "+v"(acc[0]),"+v"(acc[1]),"+v"(acc[2]),"+v"(acc[3]), \
    "+v"(acc[4]),"+v"(acc[5]),"+v"(acc[6]),"+v"(acc[7]), \
    "+v"(acc[8]),"+v"(acc[9]),"+v"(acc[10]),"+v"(acc[11]) :: ACLB)

#define LBAR asm volatile("s_waitcnt lgkmcnt(0)\n\ts_barrier" ::: ACLB, "memory")

__device__ __forceinline__ float bsel(u32x2 v, int i){
  u32 wv = (i & 2) ? (u32)v[1] : (u32)v[0];
  return __uint_as_float((i & 1) ? (wv & 0xffff0000u) : (wv << 16));
}

// gate + state update for one ut (cell = acc[.][0]; batch = quad).
// All preacts in log2 domain: sigmoid(x) = rcp(1+exp2(-xs)), tanh via exp2.
#define GATE(UT) { \
  float xz = bsel(cz, UT); \
  float xr = bsel(cr, UT); \
  float xh = bsel(ch, UT); \
  float zf = acc[UT][0]   + xz; \
  float rf = acc[4+UT][0] + xr; \
  float rh = acc[8+UT][0] + b1h[UT]; \
  zf = __builtin_amdgcn_rcpf(1.f + exp2f(-zf)); \
  rf = __builtin_amdgcn_rcpf(1.f + exp2f(-rf)); \
  float hc = xh + rf*rh; \
  float e2 = exp2f(hc); \
  float th = 1.f - 2.f*__builtin_amdgcn_rcpf(e2 + 1.f); \
  float hn = th + zf*(hpc[UT] - th); \
  hpc[UT] = hn; \
  u32 q8; asm("v_cvt_pk_fp8_f32 %0, %1, %2" : "=v"(q8) : "v"(hn), "v"(hn)); \
  hb8[nxt][quad*4][w*64 + (UT)*16 + lc] = (u8)(q8 & 0xffu); \
  if(MODE == 0) \
    hp[(UT)*16] = f2bf(hn); \
}

template<int MODE>
__global__ __launch_bounds__(256,1) void gru_scan3(
    const u16* __restrict__ xq,    // packed preacts (see gemm_bt)
    const u8*  __restrict__ rkq,   // [2][768][256] fp8 transposed recurrent kernels
    const float* __restrict__ bF, const float* __restrict__ bB,  // b[2][768] f32
    u16* __restrict__ h1out,       // MODE 0: [BT,512]
    float* __restrict__ h2out)     // MODE 1: [64,512] final states
{
  int dir = blockIdx.x & 1, bg = blockIdx.x >> 1;
  int b0 = bg*4;
  int tid = threadIdx.x;
  int w = tid>>6, l = tid&63, lc = l&15, quad = l>>4;

  __shared__ u8 hb8[2][16][272];   // double-buffered h (fp8), rows {0,4,8,12} real
  for(int i=tid; i<2*16*272; i+=256) ((u8*)hb8)[i] = 0;

  const u8* rkd = rkq + (size_t)dir*G3*U_DIM;

  // B-frags: frag(g,s,kt) -> a[((g*4+s)*2+kt)*8 .. +7]
  BINIT8(0,0,0,  0,1,2,3,4,5,6,7)        BINIT8(0,0,1,  8,9,10,11,12,13,14,15)
  BINIT8(0,1,0, 16,17,18,19,20,21,22,23) BINIT8(0,1,1, 24,25,26,27,28,29,30,31)
  BINIT8(0,2,0, 32,33,34,35,36,37,38,39) BINIT8(0,2,1, 40,41,42,43,44,45,46,47)
  BINIT8(0,3,0, 48,49,50,51,52,53,54,55) BINIT8(0,3,1, 56,57,58,59,60,61,62,63)
  BINIT8(1,0,0, 64,65,66,67,68,69,70,71) BINIT8(1,0,1, 72,73,74,75,76,77,78,79)
  BINIT8(1,1,0, 80,81,82,83,84,85,86,87) BINIT8(1,1,1, 88,89,90,91,92,93,94,95)
  BINIT8(1,2,0, 96,97,98,99,100,101,102,103) BINIT8(1,2,1, 104,105,106,107,108,109,110,111)
  BINIT8(1,3,0, 112,113,114,115,116,117,118,119) BINIT8(1,3,1, 120,121,122,123,124,125,126,127)
  BINIT8(2,0,0, 128,129,130,131,132,133,134,135) BINIT8(2,0,1, 136,137,138,139,140,141,142,143)
  BINIT8(2,1,0, 144,145,146,147,148,149,150,151) BINIT8(2,1,1, 152,153,154,155,156,157,158,159)
  BINIT8(2,2,0, 160,161,162,163,164,165,166,167) BINIT8(2,2,1, 168,169,170,171,172,173,174,175)
  BINIT8(2,3,0, 176,177,178,179,180,181,182,183) BINIT8(2,3,1, 184,185,186,187,188,189,190,191)

  // recurrent bias for h-gate only (z,r folded into gemm bias); log2-scaled
  float b1h[4];
  const float* bias1 = (dir ? bB : bF) + G3;
  #pragma unroll
  for(int ut=0; ut<4; ut++) b1h[ut] = bias1[2*U_DIM + w*64 + ut*16 + lc] * L2E2;

  int t0 = dir ? (T_LEN-1) : 0;
  long qstride = dir ? -(long)(64*3*256) : (long)(64*3*256);
  const u16* xp = xq + ((((size_t)dir*T_LEN + t0)*B_SZ + (b0+quad))*3)*256 + lc*16 + w*4;
  long hstride = dir ? -(long)(2*U_DIM) : (long)(2*U_DIM);
  u16* hp = (MODE==0)
    ? (h1out + ((size_t)(b0+quad)*T_LEN + t0)*(2*U_DIM) + dir*U_DIM + w*64 + lc)
    : nullptr;

  float hpc[4] = {0.f, 0.f, 0.f, 0.f};   // carried h (own cells), f32

  // prologue load for step 0 (pipelined: consumed this step, next prefetched)
  u32x2 cz = *(const u32x2*)(xp);
  u32x2 cr = *(const u32x2*)(xp + 256);
  u32x2 ch = *(const u32x2*)(xp + 512);

  __syncthreads();

  int cur = 0;
  for(int step=0; step<T_LEN; step++){
    AFENCE;
    int nxt = cur ^ 1;

    // A-frags: h fp8, 32 B per lane per K-tile (row lc, k = quad*32..+31)
    i8v af0, af1;
    {
      const u8* p = &hb8[cur][lc][quad*32];
      i4v lo0 = *(const i4v*)p,        hi0 = *(const i4v*)(p+16);
      i4v lo1 = *(const i4v*)(p+128),  hi1 = *(const i4v*)(p+144);
      af0 = __builtin_shufflevector(lo0, hi0, 0,1,2,3,4,5,6,7);
      af1 = __builtin_shufflevector(lo1, hi1, 0,1,2,3,4,5,6,7);
    }

    // prefetch next step's preacts (t=±512 lands in the other dir's region:
    // valid memory, values unused) — ~1 full step of latency cover
    const u16* xpn = xp + qstride;
    u32x2 czn = *(const u32x2*)(xpn);
    u32x2 crn = *(const u32x2*)(xpn + 256);
    u32x2 chn = *(const u32x2*)(xpn + 512);

    f4v acc[12];   // [g*4+ut]; cell value in reg 0 (batch = quad at row quad*4)
    // K-tile 0
    MFZ8(acc[0], af0,"a[0:7]");     MFZ8(acc[1], af0,"a[16:23]");
    MFZ8(acc[2], af0,"a[32:39]");   MFZ8(acc[3], af0,"a[48:55]");
    MFZ8(acc[4], af0,"a[64:71]");   MFZ8(acc[5], af0,"a[80:87]");
    MFZ8(acc[6], af0,"a[96:103]");  MFZ8(acc[7], af0,"a[112:119]");
    MFZ8(acc[8], af0,"a[128:135]"); MFZ8(acc[9], af0,"a[144:151]");
    MFZ8(acc[10],af0,"a[160:167]"); MFZ8(acc[11],af0,"a[176:183]");
    // K-tile 1
    MFA8(acc[0], af1,"a[8:15]");    MFA8(acc[1], af1,"a[24:31]");
    MFA8(acc[2], af1,"a[40:47]");   MFA8(acc[3], af1,"a[56:63]");
    MFA8(acc[4], af1,"a[72:79]");   MFA8(acc[5], af1,"a[88:95]");
    MFA8(acc[6], af1,"a[104:111]"); MFA8(acc[7], af1,"a[120:127]");
    MFA8(acc[8], af1,"a[136:143]"); MFA8(acc[9], af1,"a[152:159]");
    MFA8(acc[10],af1,"a[168:175]"); MFA8(acc[11],af1,"a[184:191]");
    FENCE12;

    GATE(0)
    GATE(1)
    GATE(2)
    GATE(3)

    cz = czn; cr = crn; ch = chn;
    xp = xpn;
    if(MODE==0) hp += hstride;
    LBAR;
    cur ^= 1;
  }

  // epilogue: MODE 1 final states from carried registers
  if(MODE==1){
    #pragma unroll
    for(int ut=0;ut<4;ut++)
      h2out[(size_t)(b0+quad)*(2*U_DIM) + dir*U_DIM + w*64 + ut*16 + lc] = hpc[ut];
  }
}

// ---------------- final projection + softmax (f32 output) ---------------------
__global__ void out_softmax(const float* __restrict__ h2, const float* __restrict__ wout,
                            const float* __restrict__ bout, float* __restrict__ out)
{
  __shared__ float lg[C_DIM];
  int b = blockIdx.x, l = threadIdx.x;   // 64 threads = 1 wave
  float acc[C_DIM];
  #pragma unroll
  for(int c=0;c<C_DIM;c++) acc[c] = 0.f;
  for(int k=l; k<2*U_DIM; k+=64){
    float hv = h2[b*2*U_DIM + k];
    #pragma unroll
    for(int c=0;c<C_DIM;c++) acc[c] += hv * wout[k*C_DIM + c];
  }
  #pragma unroll
  for(int c=0;c<C_DIM;c++){
    float v = acc[c];
    for(int off=32; off; off>>=1) v += __shfl_down(v, off);
    if(l==0) lg[c] = v + bout[c];
  }
  __syncthreads();
  if(l==0){
    float mx = lg[0];
    for(int c=1;c<C_DIM;c++) mx = fmaxf(mx, lg[c]);
    float sum = 0.f, ex[C_DIM];
    for(int c=0;c<C_DIM;c++){ ex[c] = __expf(lg[c]-mx); sum += ex[c]; }
    for(int c=0;c<C_DIM;c++) out[b*C_DIM + c] = ex[c]/sum;
  }
}

extern "C" void kernel_launch(void* const* d_in, const int* in_sizes, int n_in,
                              void* d_out, int out_size, void* d_ws, size_t ws_size,
                              hipStream_t stream)
{
  const int*   x    = (const int*)d_in[0];
  const float* emb  = (const float*)d_in[1];
  const float* k1f  = (const float*)d_in[2];
  const float* rk1f = (const float*)d_in[3];
  const float* b1f  = (const float*)d_in[4];
  const float* k1b  = (const float*)d_in[5];
  const float* rk1b = (const float*)d_in[6];
  const float* b1b  = (const float*)d_in[7];
  const float* k2f  = (const float*)d_in[8];
  const float* rk2f = (const float*)d_in[9];
  const float* b2f  = (const float*)d_in[10];
  const float* k2b  = (const float*)d_in[11];
  const float* rk2b = (const float*)d_in[12];
  const float* b2b  = (const float*)d_in[13];
  const float* wout = (const float*)d_in[14];
  const float* bout = (const float*)d_in[15];

  char* ws = (char*)d_ws;
  u16*  k1t   = (u16*)(ws);                       // 983,040 B     [1536,320]
  u16*  k2t   = (u16*)(ws + 983040);              // 1,572,864 B   [1536,512]
  u8*   rkq   = (u8*)(ws + 2555904);              // 786,432 B     4x[768,256] fp8
  float* h2   = (float*)(ws + 4128768);           // 131,072 B     [64,512]
  u16*  h1    = (u16*)(ws + 4259840);             // 33,554,432 B  [BT,512]
  u16*  e_pad = (u16*)(ws + 4259840);             // (alias h1)
  u16*  xq    = (u16*)(ws + 37814272);            // 100,663,296 B packed preacts

  transpose_cc<<<(NTOT*EP +255)/256,256,0,stream>>>(k1f, k1b, k1t, E_DIM, EP, NTOT);
  transpose_cc<<<(NTOT*512+255)/256,256,0,stream>>>(k2f, k2b, k2t, 512, 512, NTOT);
  transpose_fp8<<<768,256,0,stream>>>(rk1f, rkq);
  transpose_fp8<<<768,256,0,stream>>>(rk1b, rkq + 1*G3*U_DIM);
  transpose_fp8<<<768,256,0,stream>>>(rk2f, rkq + 2*G3*U_DIM);
  transpose_fp8<<<768,256,0,stream>>>(rk2b, rkq + 3*G3*U_DIM);

  embed_pad<<<(BT*EP)/256,256,0,stream>>>(x, emb, e_pad);

  // layer 1: xq = pack((e @ K1 + b0 [+ b1 for z,r]) * log2e-scale) ; scan -> h1
  gemm_bt<<<dim3(12,256),256,0,stream>>>(e_pad, k1t, xq, EP, b1f, b1b);
  gru_scan3<0><<<32,256,0,stream>>>(xq, rkq, b1f, b1b, h1, nullptr);

  // layer 2: same pipeline ; scan -> h2 (final states only)
  gemm_bt<<<dim3(12,256),256,0,stream>>>(h1, k2t, xq, 512, b2f, b2b);
  gru_scan3<1><<<32,256,0,stream>>>(xq, rkq + 2*G3*U_DIM, b2f, b2b, nullptr, h2);

  out_softmax<<<64,64,0,stream>>>(h2, wout, bout, (float*)d_out);
}

// Round 10
// 1106.761 us; speedup vs baseline: 1.0838x; 1.0838x over previous
//
#include <hip/hip_runtime.h>

typedef unsigned char  u8;
typedef unsigned short u16;
typedef unsigned int   u32;
typedef unsigned long long u64;
typedef __attribute__((ext_vector_type(8))) short s8v;   // 8 x bf16 bits (4 VGPRs)
typedef __attribute__((ext_vector_type(4))) float f4v;   // MFMA accumulator
typedef __attribute__((ext_vector_type(4))) int   i4v;   // 4 VGPRs (generic 16B)
typedef __attribute__((ext_vector_type(8))) int   i8v;   // 8 VGPRs (fp8 MFMA operand)
typedef __attribute__((ext_vector_type(2))) unsigned int u32x2;

#define B_SZ  64
#define T_LEN 512
#define U_DIM 256
#define E_DIM 300
#define EP    320          // E padded to multiple of 32
#define G3    768          // 3*U
#define NTOT  1536         // both directions concatenated
#define C_DIM 20
#define BT    (B_SZ*T_LEN)

// log2(e) scales folded into weights/biases so gates use a single v_exp_f32
#define L2E  1.44269504088896f
#define L2E2 2.88539008177793f

__device__ __forceinline__ float bf2f(u16 h){ return __uint_as_float(((u32)h)<<16); }
__device__ __forceinline__ u16 f2bf(float f){
  u32 u = __float_as_uint(f);
  u32 r = (u + 0x7FFFu + ((u>>16)&1u)) >> 16;   // RNE
  return (u16)r;
}

// f32 -> OCP e4m3fn, RNE, handles subnormals + 448 clamp (prep kernels only)
__device__ __forceinline__ u8 f2fp8(float f){
  u32 u = __float_as_uint(f);
  u32 s = (u>>24)&0x80u;
  u32 au = u & 0x7fffffffu;
  if(au < 0x3C800000u){                       // |f| < 2^-6: subnormal range
    float m = rintf(__uint_as_float(au) * 512.f);   // 0..8 (RNE)
    return (u8)(s | (u32)(int)m);             // m==8 -> 0x08 == 2^-6 normal
  }
  int e = (int)(au>>23) - 127;
  u32 mant = au & 0x7fffffu;
  u32 lsb = (mant>>20)&1u;
  mant += 0x7FFFFu + lsb;                     // RNE to 3 mantissa bits
  if(mant >> 23){ mant = 0; e += 1; }
  if(e > 8 || (e==8 && ((mant>>20)&7u)==7u)) return (u8)(s | 0x7Eu);  // clamp 448
  return (u8)(s | ((u32)(e+7)<<3) | ((mant>>20)&7u));
}

// ------------- embedding gather f32 -> bf16, K-pad (300 -> 320, zeros) --------
__global__ void embed_pad(const int* __restrict__ x, const float* __restrict__ emb,
                          u16* __restrict__ e){
  int idx = blockIdx.x*256 + threadIdx.x;
  if(idx >= BT*EP) return;
  int row = idx / EP, col = idx - row*EP;
  u16 v = 0;
  if(col < E_DIM) v = f2bf(emb[(size_t)x[row]*E_DIM + col]);
  e[idx] = v;
}

// ------ transpose + concat two f32 [K,768] sources -> bf16 dst[N][Kp] ---------
// Gate-dependent log2e scale folded into the input-projection weights.
__global__ void transpose_cc(const float* __restrict__ A, const float* __restrict__ Bm,
                             u16* __restrict__ dst, int K, int Kp, int N){
  int idx = blockIdx.x*256 + threadIdx.x;
  if(idx >= N*Kp) return;
  int n = idx / Kp, k = idx - n*Kp;
  u16 v = 0;
  if(k < K){
    const float* s = (n < G3) ? A : Bm;
    int nn = (n < G3) ? n : n - G3;
    float sc = ((nn>>8)==2) ? L2E2 : L2E;
    v = f2bf(s[(size_t)k*G3 + nn] * sc);
  }
  dst[idx] = v;
}

// ------ recurrent kernel f32 [256][768] -> fp8 e4m3 transposed [768][256] -----
// Same gate-dependent log2e scale folded into the recurrent weights.
__global__ void transpose_fp8(const float* __restrict__ rk, u8* __restrict__ dst){
  int idx = blockIdx.x*256 + threadIdx.x;     // 768*256
  if(idx >= G3*U_DIM) return;
  int n = idx >> 8, k = idx & 255;
  float sc = ((n>>8)==2) ? L2E2 : L2E;
  dst[idx] = f2fp8(rk[(size_t)k*G3 + n] * sc);
}

// ------- GEMM: packed preacts for the M=4 scan -------------------------------
// xq layout (u16): [dir][t][b][g][lc16][ut16]; total 2*512*64*3*256 u16.
// Recurrent bias b[1] for gates z,r (g<2) is folded in here; biases carry the
// same log2e gate scale as the weights (preacts live in log2 domain).
__global__ __launch_bounds__(256) void gemm_bt(
    const u16* __restrict__ A, const u16* __restrict__ BT_, u16* __restrict__ Cq,
    int Kp, const float* __restrict__ biasA, const float* __restrict__ biasB)
{
  __shared__ u16 Al[128][40];   // +8 pad breaks bank collisions
  __shared__ u16 Bl[128][40];
  int tid = threadIdx.x;
  int w = tid>>6, l = tid&63, lc = l&15, quad = l>>4;
  int wm = w>>1, wn = w&1;
  int nb = blockIdx.x*128;
  int bg4 = blockIdx.y >> 4, tg = blockIdx.y & 15;
  int b0r = bg4*4, tb0 = tg*32;

  f4v acc[4][4];
  #pragma unroll
  for(int i=0;i<4;i++)
    #pragma unroll
    for(int j=0;j<4;j++) acc[i][j] = (f4v){0.f,0.f,0.f,0.f};

  int nk = Kp >> 5;
  for(int kt=0; kt<nk; kt++){
    __syncthreads();
    {
      int c0 = tid, c1 = tid + 256;
      int r0 = c0>>2, k80 = c0&3;
      int r1 = c1>>2, k81 = c1&3;
      size_t ga0 = ((size_t)(b0r + (r0&3))*T_LEN + tb0 + (r0>>2))*Kp;
      size_t ga1 = ((size_t)(b0r + (r1&3))*T_LEN + tb0 + (r1>>2))*Kp;
      *(s8v*)&Al[r0][k80*8] = *(const s8v*)(A + ga0 + kt*32 + k80*8);
      *(s8v*)&Al[r1][k81*8] = *(const s8v*)(A + ga1 + kt*32 + k81*8);
      *(s8v*)&Bl[r0][k80*8] = *(const s8v*)(BT_ + (size_t)(nb+r0)*Kp + kt*32 + k80*8);
      *(s8v*)&Bl[r1][k81*8] = *(const s8v*)(BT_ + (size_t)(nb+r1)*Kp + kt*32 + k81*8);
    }
    __syncthreads();
    s8v af[4], bf[4];
    #pragma unroll
    for(int i=0;i<4;i++) af[i] = *(const s8v*)&Al[wm*64 + i*16 + lc][quad*8];
    #pragma unroll
    for(int j=0;j<4;j++) bf[j] = *(const s8v*)&Bl[wn*64 + j*16 + lc][quad*8];
    #pragma unroll
    for(int i=0;i<4;i++)
      #pragma unroll
      for(int j=0;j<4;j++)
        acc[i][j] = __builtin_amdgcn_mfma_f32_16x16x32_bf16(af[i], bf[j], acc[i][j],0,0,0);
  }

  // packed epilogue -> xq[dir][t][b][g][lc][ut], one u64 (4 ut) per (i,r)
  int dirq = (nb >= G3) ? 1 : 0;
  int c7b  = nb - dirq*G3 + wn*64;      // col within dir, minus lc and j*16
  int g    = c7b >> 8;
  int ut0  = (c7b >> 4) & 15;
  const float* bb = dirq ? biasB : biasA;
  float gsc = (g < 2) ? L2E : L2E2;
  float bj[4];
  #pragma unroll
  for(int j=0;j<4;j++){
    int cc = c7b + j*16 + lc;
    bj[j] = (bb[cc] + ((g < 2) ? bb[G3 + cc] : 0.f)) * gsc;  // fold b[1] for z,r
  }
  #pragma unroll
  for(int i=0;i<4;i++){
    int t = tb0 + wm*16 + i*4 + quad;
    size_t base = ((((size_t)dirq*T_LEN + t)*B_SZ + b0r)*3 + g)*256 + lc*16 + ut0;
    #pragma unroll
    for(int r=0;r<4;r++){
      u16 p0 = f2bf(acc[i][0][r] + bj[0]);
      u16 p1 = f2bf(acc[i][1][r] + bj[1]);
      u16 p2 = f2bf(acc[i][2][r] + bj[2]);
      u16 p3 = f2bf(acc[i][3][r] + bj[3]);
      *(u64*)(Cq + base + (size_t)r*768) =
        (u64)p0 | ((u64)p1<<16) | ((u64)p2<<32) | ((u64)p3<<48);
    }
  }
}

// ---------------- GRU scan: fp8 K=128 MFMA, register-resident weights --------
// 32 blocks (dir x 16 batch-groups of 4) x 256 threads (4 waves, 1 wave/SIMD).
// Per wave: 192 N-cols (3 gates x 64 u) x K=256 fp8 -> 24 B-frags x 8 AGPRs =
// a0..a191. h exchanged per step via LDS as fp8 bytes; gate state in f32.
// 24 MFMAs/step/wave (12 N-tiles x 2 K-tiles of 16x16x128).
// xq preact loads pipelined one step ahead. Preacts/weights pre-scaled by
// log2e (z,r) / 2*log2e (h); gates use raw v_exp_f32 (single instruction,
// not OCML exp2f which adds guard code — R9 lesson).

#define ACLB \
 "a0","a1","a2","a3","a4","a5","a6","a7","a8","a9","a10","a11","a12","a13","a14","a15", \
 "a16","a17","a18","a19","a20","a21","a22","a23","a24","a25","a26","a27","a28","a29","a30","a31", \
 "a32","a33","a34","a35","a36","a37","a38","a39","a40","a41","a42","a43","a44","a45","a46","a47", \
 "a48","a49","a50","a51","a52","a53","a54","a55","a56","a57","a58","a59","a60","a61","a62","a63", \
 "a64","a65","a66","a67","a68","a69","a70","a71","a72","a73","a74","a75","a76","a77","a78","a79", \
 "a80","a81","a82","a83","a84","a85","a86","a87","a88","a89","a90","a91","a92","a93","a94","a95", \
 "a96","a97","a98","a99","a100","a101","a102","a103","a104","a105","a106","a107","a108","a109","a110","a111", \
 "a112","a113","a114","a115","a116","a117","a118","a119","a120","a121","a122","a123","a124","a125","a126","a127", \
 "a128","a129","a130","a131","a132","a133","a134","a135","a136","a137","a138","a139","a140","a141","a142","a143", \
 "a144","a145","a146","a147","a148","a149","a150","a151","a152","a153","a154","a155","a156","a157","a158","a159", \
 "a160","a161","a162","a163","a164","a165","a166","a167","a168","a169","a170","a171","a172","a173","a174","a175", \
 "a176","a177","a178","a179","a180","a181","a182","a183","a184","a185","a186","a187","a188","a189","a190","a191"

#define AFENCE asm volatile("" ::: ACLB)

#define BINIT8(G,S,KT,A0,A1,A2,A3,A4,A5,A6,A7) { \
  const u8* p = rkd + ((size_t)((G)*256 + w*64 + (S)*16 + lc)<<8) + (KT)*128 + quad*32; \
  i4v t0 = *(const i4v*)p; \
  i4v t1 = *(const i4v*)(p+16); \
  asm volatile("v_accvgpr_write_b32 a" #A0 ", %0\n\t" \
               "v_accvgpr_write_b32 a" #A1 ", %1\n\t" \
               "v_accvgpr_write_b32 a" #A2 ", %2\n\t" \
               "v_accvgpr_write_b32 a" #A3 ", %3\n\t" \
               "v_accvgpr_write_b32 a" #A4 ", %4\n\t" \
               "v_accvgpr_write_b32 a" #A5 ", %5\n\t" \
               "v_accvgpr_write_b32 a" #A6 ", %6\n\t" \
               "v_accvgpr_write_b32 a" #A7 ", %7" \
               :: "v"(t0[0]),"v"(t0[1]),"v"(t0[2]),"v"(t0[3]), \
                  "v"(t1[0]),"v"(t1[1]),"v"(t1[2]),"v"(t1[3]) : ACLB); }

// fp8 K=128 MFMA, B from AGPR (cbsz/blgp default 0 = e4m3 both operands)
#define MFZ8(ACC,AF,AR) \
  asm("v_mfma_f32_16x16x128_f8f6f4 %0, %1, " AR ", 0" : "=&v"(ACC) : "v"(AF))
#define MFA8(ACC,AF,AR) \
  asm("v_mfma_f32_16x16x128_f8f6f4 %0, %1, " AR ", %0" : "+v"(ACC) : "v"(AF))

// MFMA->VALU hazard fence: orders all acc reads after 16 nop cycles
#define FENCE12 asm volatile("s_nop 7\n\ts_nop 7" \
  : "+v"(acc[0]),"+v"(acc[1]),"+v"(acc[2]),"+v"(acc[3]), \
    "+v"(acc[4]),"+v"(acc[5]),"+v"(acc[6]),"+v"(acc[7]), \
    "+v"(acc[8]),"+v"(acc[9]),"+v"(acc[10]),"+v"(acc[11]) :: ACLB)

#define LBAR asm volatile("s_waitcnt lgkmcnt(0)\n\ts_barrier" ::: ACLB, "memory")

__device__ __forceinline__ float bsel(u32x2 v, int i){
  u32 wv = (i & 2) ? (u32)v[1] : (u32)v[0];
  return __uint_as_float((i & 1) ? (wv & 0xffff0000u) : (wv << 16));
}

// gate + state update for one ut (cell = acc[.][0]; batch = quad).
// Preacts in log2 domain: sigmoid(x)=rcp(1+2^(-xs)), tanh via 2^(hc_scaled).
// Raw v_exp_f32 (D=2^S0); -src modifier is free (VOP3).
#define GATE(UT) { \
  float xz = bsel(cz, UT); \
  float xr = bsel(cr, UT); \
  float xh = bsel(ch, UT); \
  float zf = acc[UT][0]   + xz; \
  float rf = acc[4+UT][0] + xr; \
  float rh = acc[8+UT][0] + b1h[UT]; \
  float ez, er, e2; \
  asm("v_exp_f32 %0, -%1" : "=v"(ez) : "v"(zf)); \
  asm("v_exp_f32 %0, -%1" : "=v"(er) : "v"(rf)); \
  zf = __builtin_amdgcn_rcpf(1.f + ez); \
  rf = __builtin_amdgcn_rcpf(1.f + er); \
  float hc = xh + rf*rh; \
  asm("v_exp_f32 %0, %1" : "=v"(e2) : "v"(hc)); \
  float th = 1.f - 2.f*__builtin_amdgcn_rcpf(e2 + 1.f); \
  float hn = th + zf*(hpc[UT] - th); \
  hpc[UT] = hn; \
  u32 q8; asm("v_cvt_pk_fp8_f32 %0, %1, %2" : "=v"(q8) : "v"(hn), "v"(hn)); \
  hb8[nxt][quad*4][w*64 + (UT)*16 + lc] = (u8)(q8 & 0xffu); \
  if(MODE == 0) \
    hp[(UT)*16] = f2bf(hn); \
}

template<int MODE>
__global__ __launch_bounds__(256,1) void gru_scan3(
    const u16* __restrict__ xq,    // packed preacts (see gemm_bt)
    const u8*  __restrict__ rkq,   // [2][768][256] fp8 transposed recurrent kernels
    const float* __restrict__ bF, const float* __restrict__ bB,  // b[2][768] f32
    u16* __restrict__ h1out,       // MODE 0: [BT,512]
    float* __restrict__ h2out)     // MODE 1: [64,512] final states
{
  int dir = blockIdx.x & 1, bg = blockIdx.x >> 1;
  int b0 = bg*4;
  int tid = threadIdx.x;
  int w = tid>>6, l = tid&63, lc = l&15, quad = l>>4;

  __shared__ u8 hb8[2][16][272];   // double-buffered h (fp8), rows {0,4,8,12} real
  for(int i=tid; i<2*16*272; i+=256) ((u8*)hb8)[i] = 0;

  const u8* rkd = rkq + (size_t)dir*G3*U_DIM;

  // B-frags: frag(g,s,kt) -> a[((g*4+s)*2+kt)*8 .. +7]
  BINIT8(0,0,0,  0,1,2,3,4,5,6,7)        BINIT8(0,0,1,  8,9,10,11,12,13,14,15)
  BINIT8(0,1,0, 16,17,18,19,20,21,22,23) BINIT8(0,1,1, 24,25,26,27,28,29,30,31)
  BINIT8(0,2,0, 32,33,34,35,36,37,38,39) BINIT8(0,2,1, 40,41,42,43,44,45,46,47)
  BINIT8(0,3,0, 48,49,50,51,52,53,54,55) BINIT8(0,3,1, 56,57,58,59,60,61,62,63)
  BINIT8(1,0,0, 64,65,66,67,68,69,70,71) BINIT8(1,0,1, 72,73,74,75,76,77,78,79)
  BINIT8(1,1,0, 80,81,82,83,84,85,86,87) BINIT8(1,1,1, 88,89,90,91,92,93,94,95)
  BINIT8(1,2,0, 96,97,98,99,100,101,102,103) BINIT8(1,2,1, 104,105,106,107,108,109,110,111)
  BINIT8(1,3,0, 112,113,114,115,116,117,118,119) BINIT8(1,3,1, 120,121,122,123,124,125,126,127)
  BINIT8(2,0,0, 128,129,130,131,132,133,134,135) BINIT8(2,0,1, 136,137,138,139,140,141,142,143)
  BINIT8(2,1,0, 144,145,146,147,148,149,150,151) BINIT8(2,1,1, 152,153,154,155,156,157,158,159)
  BINIT8(2,2,0, 160,161,162,163,164,165,166,167) BINIT8(2,2,1, 168,169,170,171,172,173,174,175)
  BINIT8(2,3,0, 176,177,178,179,180,181,182,183) BINIT8(2,3,1, 184,185,186,187,188,189,190,191)

  // recurrent bias for h-gate only (z,r folded into gemm bias); log2-scaled
  float b1h[4];
  const float* bias1 = (dir ? bB : bF) + G3;
  #pragma unroll
  for(int ut=0; ut<4; ut++) b1h[ut] = bias1[2*U_DIM + w*64 + ut*16 + lc] * L2E2;

  int t0 = dir ? (T_LEN-1) : 0;
  long qstride = dir ? -(long)(64*3*256) : (long)(64*3*256);
  const u16* xp = xq + ((((size_t)dir*T_LEN + t0)*B_SZ + (b0+quad))*3)*256 + lc*16 + w*4;
  long hstride = dir ? -(long)(2*U_DIM) : (long)(2*U_DIM);
  u16* hp = (MODE==0)
    ? (h1out + ((size_t)(b0+quad)*T_LEN + t0)*(2*U_DIM) + dir*U_DIM + w*64 + lc)
    : nullptr;

  float hpc[4] = {0.f, 0.f, 0.f, 0.f};   // carried h (own cells), f32

  // prologue load for step 0 (pipelined: consumed this step, next prefetched)
  u32x2 cz = *(const u32x2*)(xp);
  u32x2 cr = *(const u32x2*)(xp + 256);
  u32x2 ch = *(const u32x2*)(xp + 512);

  __syncthreads();

  int cur = 0;
  for(int step=0; step<T_LEN; step++){
    AFENCE;
    int nxt = cur ^ 1;

    // A-frags: h fp8, 32 B per lane per K-tile (row lc, k = quad*32..+31)
    i8v af0, af1;
    {
      const u8* p = &hb8[cur][lc][quad*32];
      i4v lo0 = *(const i4v*)p,        hi0 = *(const i4v*)(p+16);
      i4v lo1 = *(const i4v*)(p+128),  hi1 = *(const i4v*)(p+144);
      af0 = __builtin_shufflevector(lo0, hi0, 0,1,2,3,4,5,6,7);
      af1 = __builtin_shufflevector(lo1, hi1, 0,1,2,3,4,5,6,7);
    }

    // prefetch next step's preacts (t=±512 lands in the other dir's region:
    // valid memory, values unused) — ~1 full step of latency cover
    const u16* xpn = xp + qstride;
    u32x2 czn = *(const u32x2*)(xpn);
    u32x2 crn = *(const u32x2*)(xpn + 256);
    u32x2 chn = *(const u32x2*)(xpn + 512);

    f4v acc[12];   // [g*4+ut]; cell value in reg 0 (batch = quad at row quad*4)
    // K-tile 0
    MFZ8(acc[0], af0,"a[0:7]");     MFZ8(acc[1], af0,"a[16:23]");
    MFZ8(acc[2], af0,"a[32:39]");   MFZ8(acc[3], af0,"a[48:55]");
    MFZ8(acc[4], af0,"a[64:71]");   MFZ8(acc[5], af0,"a[80:87]");
    MFZ8(acc[6], af0,"a[96:103]");  MFZ8(acc[7], af0,"a[112:119]");
    MFZ8(acc[8], af0,"a[128:135]"); MFZ8(acc[9], af0,"a[144:151]");
    MFZ8(acc[10],af0,"a[160:167]"); MFZ8(acc[11],af0,"a[176:183]");
    // K-tile 1
    MFA8(acc[0], af1,"a[8:15]");    MFA8(acc[1], af1,"a[24:31]");
    MFA8(acc[2], af1,"a[40:47]");   MFA8(acc[3], af1,"a[56:63]");
    MFA8(acc[4], af1,"a[72:79]");   MFA8(acc[5], af1,"a[88:95]");
    MFA8(acc[6], af1,"a[104:111]"); MFA8(acc[7], af1,"a[120:127]");
    MFA8(acc[8], af1,"a[136:143]"); MFA8(acc[9], af1,"a[152:159]");
    MFA8(acc[10],af1,"a[168:175]"); MFA8(acc[11],af1,"a[184:191]");
    FENCE12;

    GATE(0)
    GATE(1)
    GATE(2)
    GATE(3)

    cz = czn; cr = crn; ch = chn;
    xp = xpn;
    if(MODE==0) hp += hstride;
    LBAR;
    cur ^= 1;
  }

  // epilogue: MODE 1 final states from carried registers
  if(MODE==1){
    #pragma unroll
    for(int ut=0;ut<4;ut++)
      h2out[(size_t)(b0+quad)*(2*U_DIM) + dir*U_DIM + w*64 + ut*16 + lc] = hpc[ut];
  }
}

// ---------------- final projection + softmax (f32 output) ---------------------
__global__ void out_softmax(const float* __restrict__ h2, const float* __restrict__ wout,
                            const float* __restrict__ bout, float* __restrict__ out)
{
  __shared__ float lg[C_DIM];
  int b = blockIdx.x, l = threadIdx.x;   // 64 threads = 1 wave
  float acc[C_DIM];
  #pragma unroll
  for(int c=0;c<C_DIM;c++) acc[c] = 0.f;
  for(int k=l; k<2*U_DIM; k+=64){
    float hv = h2[b*2*U_DIM + k];
    #pragma unroll
    for(int c=0;c<C_DIM;c++) acc[c] += hv * wout[k*C_DIM + c];
  }
  #pragma unroll
  for(int c=0;c<C_DIM;c++){
    float v = acc[c];
    for(int off=32; off; off>>=1) v += __shfl_down(v, off);
    if(l==0) lg[c] = v + bout[c];
  }
  __syncthreads();
  if(l==0){
    float mx = lg[0];
    for(int c=1;c<C_DIM;c++) mx = fmaxf(mx, lg[c]);
    float sum = 0.f, ex[C_DIM];
    for(int c=0;c<C_DIM;c++){ ex[c] = __expf(lg[c]-mx); sum += ex[c]; }
    for(int c=0;c<C_DIM;c++) out[b*C_DIM + c] = ex[c]/sum;
  }
}

extern "C" void kernel_launch(void* const* d_in, const int* in_sizes, int n_in,
                              void* d_out, int out_size, void* d_ws, size_t ws_size,
                              hipStream_t stream)
{
  const int*   x    = (const int*)d_in[0];
  const float* emb  = (const float*)d_in[1];
  const float* k1f  = (const float*)d_in[2];
  const float* rk1f = (const float*)d_in[3];
  const float* b1f  = (const float*)d_in[4];
  const float* k1b  = (const float*)d_in[5];
  const float* rk1b = (const float*)d_in[6];
  const float* b1b  = (const float*)d_in[7];
  const float* k2f  = (const float*)d_in[8];
  const float* rk2f = (const float*)d_in[9];
  const float* b2f  = (const float*)d_in[10];
  const float* k2b  = (const float*)d_in[11];
  const float* rk2b = (const float*)d_in[12];
  const float* b2b  = (const float*)d_in[13];
  const float* wout = (const float*)d_in[14];
  const float* bout = (const float*)d_in[15];

  char* ws = (char*)d_ws;
  u16*  k1t   = (u16*)(ws);                       // 983,040 B     [1536,320]
  u16*  k2t   = (u16*)(ws + 983040);              // 1,572,864 B   [1536,512]
  u8*   rkq   = (u8*)(ws + 2555904);              // 786,432 B     4x[768,256] fp8
  float* h2   = (float*)(ws + 4128768);           // 131,072 B     [64,512]
  u16*  h1    = (u16*)(ws + 4259840);             // 33,554,432 B  [BT,512]
  u16*  e_pad = (u16*)(ws + 4259840);             // (alias h1)
  u16*  xq    = (u16*)(ws + 37814272);            // 100,663,296 B packed preacts

  transpose_cc<<<(NTOT*EP +255)/256,256,0,stream>>>(k1f, k1b, k1t, E_DIM, EP, NTOT);
  transpose_cc<<<(NTOT*512+255)/256,256,0,stream>>>(k2f, k2b, k2t, 512, 512, NTOT);
  transpose_fp8<<<768,256,0,stream>>>(rk1f, rkq);
  transpose_fp8<<<768,256,0,stream>>>(rk1b, rkq + 1*G3*U_DIM);
  transpose_fp8<<<768,256,0,stream>>>(rk2f, rkq + 2*G3*U_DIM);
  transpose_fp8<<<768,256,0,stream>>>(rk2b, rkq + 3*G3*U_DIM);

  embed_pad<<<(BT*EP)/256,256,0,stream>>>(x, emb, e_pad);

  // layer 1: xq = pack((e @ K1 + b0 [+ b1 for z,r]) * log2e-scale) ; scan -> h1
  gemm_bt<<<dim3(12,256),256,0,stream>>>(e_pad, k1t, xq, EP, b1f, b1b);
  gru_scan3<0><<<32,256,0,stream>>>(xq, rkq, b1f, b1b, h1, nullptr);

  // layer 2: same pipeline ; scan -> h2 (final states only)
  gemm_bt<<<dim3(12,256),256,0,stream>>>(h1, k2t, xq, 512, b2f, b2b);
  gru_scan3<1><<<32,256,0,stream>>>(xq, rkq + 2*G3*U_DIM, b2f, b2b, nullptr, h2);

  out_softmax<<<64,64,0,stream>>>(h2, wout, bout, (float*)d_out);
}

// Round 11
// 1101.256 us; speedup vs baseline: 1.0892x; 1.0050x over previous
//
#include <hip/hip_runtime.h>

typedef unsigned char  u8;
typedef unsigned short u16;
typedef unsigned int   u32;
typedef unsigned long long u64;
typedef __attribute__((ext_vector_type(8))) short s8v;   // 8 x bf16 bits (4 VGPRs)
typedef __attribute__((ext_vector_type(4))) float f4v;   // MFMA accumulator
typedef __attribute__((ext_vector_type(4))) int   i4v;   // 4 VGPRs (generic 16B)
typedef __attribute__((ext_vector_type(8))) int   i8v;   // 8 VGPRs (fp8 MFMA operand)
typedef __attribute__((ext_vector_type(2))) unsigned int u32x2;

#define B_SZ  64
#define T_LEN 512
#define U_DIM 256
#define E_DIM 300
#define EP    320          // E padded to multiple of 32
#define G3    768          // 3*U
#define NTOT  1536         // both directions concatenated
#define C_DIM 20
#define BT    (B_SZ*T_LEN)

// log2(e) scales folded into weights/biases so gates use a single v_exp_f32
#define L2E  1.44269504088896f
#define L2E2 2.88539008177793f

__device__ __forceinline__ float bf2f(u16 h){ return __uint_as_float(((u32)h)<<16); }
__device__ __forceinline__ u16 f2bf(float f){
  u32 u = __float_as_uint(f);
  u32 r = (u + 0x7FFFu + ((u>>16)&1u)) >> 16;   // RNE
  return (u16)r;
}

// f32 -> OCP e4m3fn, RNE, handles subnormals + 448 clamp (prep kernels only)
__device__ __forceinline__ u8 f2fp8(float f){
  u32 u = __float_as_uint(f);
  u32 s = (u>>24)&0x80u;
  u32 au = u & 0x7fffffffu;
  if(au < 0x3C800000u){                       // |f| < 2^-6: subnormal range
    float m = rintf(__uint_as_float(au) * 512.f);   // 0..8 (RNE)
    return (u8)(s | (u32)(int)m);             // m==8 -> 0x08 == 2^-6 normal
  }
  int e = (int)(au>>23) - 127;
  u32 mant = au & 0x7fffffu;
  u32 lsb = (mant>>20)&1u;
  mant += 0x7FFFFu + lsb;                     // RNE to 3 mantissa bits
  if(mant >> 23){ mant = 0; e += 1; }
  if(e > 8 || (e==8 && ((mant>>20)&7u)==7u)) return (u8)(s | 0x7Eu);  // clamp 448
  return (u8)(s | ((u32)(e+7)<<3) | ((mant>>20)&7u));
}

// ------------- embedding gather f32 -> bf16, K-pad (300 -> 320, zeros) --------
__global__ void embed_pad(const int* __restrict__ x, const float* __restrict__ emb,
                          u16* __restrict__ e){
  int idx = blockIdx.x*256 + threadIdx.x;
  if(idx >= BT*EP) return;
  int row = idx / EP, col = idx - row*EP;
  u16 v = 0;
  if(col < E_DIM) v = f2bf(emb[(size_t)x[row]*E_DIM + col]);
  e[idx] = v;
}

// ------ transpose + concat two f32 [K,768] sources -> bf16 dst[N][Kp] ---------
// Gate-dependent log2e scale folded into the input-projection weights.
__global__ void transpose_cc(const float* __restrict__ A, const float* __restrict__ Bm,
                             u16* __restrict__ dst, int K, int Kp, int N){
  int idx = blockIdx.x*256 + threadIdx.x;
  if(idx >= N*Kp) return;
  int n = idx / Kp, k = idx - n*Kp;
  u16 v = 0;
  if(k < K){
    const float* s = (n < G3) ? A : Bm;
    int nn = (n < G3) ? n : n - G3;
    float sc = ((nn>>8)==2) ? L2E2 : L2E;
    v = f2bf(s[(size_t)k*G3 + nn] * sc);
  }
  dst[idx] = v;
}

// ------ recurrent kernel f32 [256][768] -> fp8 e4m3 transposed [768][256] -----
// Same gate-dependent log2e scale folded into the recurrent weights.
__global__ void transpose_fp8(const float* __restrict__ rk, u8* __restrict__ dst){
  int idx = blockIdx.x*256 + threadIdx.x;     // 768*256
  if(idx >= G3*U_DIM) return;
  int n = idx >> 8, k = idx & 255;
  float sc = ((n>>8)==2) ? L2E2 : L2E;
  dst[idx] = f2fp8(rk[(size_t)k*G3 + n] * sc);
}

// ------- GEMM: packed preacts for the M=4 scan -------------------------------
// xq layout (u16): [dir][t][b][g][lc16][ut16]; total 2*512*64*3*256 u16.
// Double-buffered LDS pipeline: ONE barrier per K-step; next tile's global
// loads issue right after the barrier and their latency hides under the
// current tile's ds_read+MFMA phase (R11: was 2 barriers + exposed latency).
__global__ __launch_bounds__(256) void gemm_bt(
    const u16* __restrict__ A, const u16* __restrict__ BT_, u16* __restrict__ Cq,
    int Kp, const float* __restrict__ biasA, const float* __restrict__ biasB)
{
  __shared__ u16 Al[2][128][40];   // +8 pad breaks bank collisions
  __shared__ u16 Bl[2][128][40];
  int tid = threadIdx.x;
  int w = tid>>6, l = tid&63, lc = l&15, quad = l>>4;
  int wm = w>>1, wn = w&1;
  int nb = blockIdx.x*128;
  int bg4 = blockIdx.y >> 4, tg = blockIdx.y & 15;
  int b0r = bg4*4, tb0 = tg*32;

  f4v acc[4][4];
  #pragma unroll
  for(int i=0;i<4;i++)
    #pragma unroll
    for(int j=0;j<4;j++) acc[i][j] = (f4v){0.f,0.f,0.f,0.f};

  // staging geometry: thread -> (row r0 & r0+64, 8-elem k-block k8)
  int r0 = tid>>2, k8 = tid&3;
  int r1 = r0 + 64;
  const u16* pa0 = A + ((size_t)(b0r + (r0&3))*T_LEN + tb0 + (r0>>2))*Kp + k8*8;
  const u16* pa1 = A + ((size_t)(b0r + (r1&3))*T_LEN + tb0 + (r1>>2))*Kp + k8*8;
  const u16* pb0 = BT_ + (size_t)(nb+r0)*Kp + k8*8;
  const u16* pb1 = BT_ + (size_t)(nb+r1)*Kp + k8*8;

  // prologue: K-tile 0 into registers
  s8v ra0 = *(const s8v*)pa0, ra1 = *(const s8v*)pa1;
  s8v rb0 = *(const s8v*)pb0, rb1 = *(const s8v*)pb1;

  int nk = Kp >> 5;
  int cur = 0;
  for(int kt=0; kt<nk; kt++){
    *(s8v*)&Al[cur][r0][k8*8] = ra0;
    *(s8v*)&Al[cur][r1][k8*8] = ra1;
    *(s8v*)&Bl[cur][r0][k8*8] = rb0;
    *(s8v*)&Bl[cur][r1][k8*8] = rb1;
    __syncthreads();
    if(kt+1 < nk){
      int off = (kt+1)*32;
      ra0 = *(const s8v*)(pa0 + off);
      ra1 = *(const s8v*)(pa1 + off);
      rb0 = *(const s8v*)(pb0 + off);
      rb1 = *(const s8v*)(pb1 + off);
    }
    s8v af[4], bf[4];
    #pragma unroll
    for(int i=0;i<4;i++) af[i] = *(const s8v*)&Al[cur][wm*64 + i*16 + lc][quad*8];
    #pragma unroll
    for(int j=0;j<4;j++) bf[j] = *(const s8v*)&Bl[cur][wn*64 + j*16 + lc][quad*8];
    #pragma unroll
    for(int i=0;i<4;i++)
      #pragma unroll
      for(int j=0;j<4;j++)
        acc[i][j] = __builtin_amdgcn_mfma_f32_16x16x32_bf16(af[i], bf[j], acc[i][j],0,0,0);
    cur ^= 1;
  }

  // packed epilogue -> xq[dir][t][b][g][lc][ut], one u64 (4 ut) per (i,r)
  int dirq = (nb >= G3) ? 1 : 0;
  int c7b  = nb - dirq*G3 + wn*64;      // col within dir, minus lc and j*16
  int g    = c7b >> 8;
  int ut0  = (c7b >> 4) & 15;
  const float* bb = dirq ? biasB : biasA;
  float gsc = (g < 2) ? L2E : L2E2;
  float bj[4];
  #pragma unroll
  for(int j=0;j<4;j++){
    int cc = c7b + j*16 + lc;
    bj[j] = (bb[cc] + ((g < 2) ? bb[G3 + cc] : 0.f)) * gsc;  // fold b[1] for z,r
  }
  #pragma unroll
  for(int i=0;i<4;i++){
    int t = tb0 + wm*16 + i*4 + quad;
    size_t base = ((((size_t)dirq*T_LEN + t)*B_SZ + b0r)*3 + g)*256 + lc*16 + ut0;
    #pragma unroll
    for(int r=0;r<4;r++){
      u16 p0 = f2bf(acc[i][0][r] + bj[0]);
      u16 p1 = f2bf(acc[i][1][r] + bj[1]);
      u16 p2 = f2bf(acc[i][2][r] + bj[2]);
      u16 p3 = f2bf(acc[i][3][r] + bj[3]);
      *(u64*)(Cq + base + (size_t)r*768) =
        (u64)p0 | ((u64)p1<<16) | ((u64)p2<<32) | ((u64)p3<<48);
    }
  }
}

// ---------------- GRU scan: fp8 K=128 MFMA, register-resident weights --------
// 32 blocks (dir x 16 batch-groups of 4) x 256 threads (4 waves, 1 wave/SIMD).
// Per wave: 192 N-cols (3 gates x 64 u) x K=256 fp8 -> 24 B-frags x 8 AGPRs =
// a0..a191. h exchanged per step via LDS as fp8 bytes; gate state in f32.
// 24 MFMAs/step/wave (12 N-tiles x 2 K-tiles of 16x16x128).
// xq preact loads pipelined one step ahead. Preacts/weights pre-scaled by
// log2e (z,r) / 2*log2e (h); gates use raw v_exp_f32 (single instruction,
// not OCML exp2f which adds guard code — R9 lesson).

#define ACLB \
 "a0","a1","a2","a3","a4","a5","a6","a7","a8","a9","a10","a11","a12","a13","a14","a15", \
 "a16","a17","a18","a19","a20","a21","a22","a23","a24","a25","a26","a27","a28","a29","a30","a31", \
 "a32","a33","a34","a35","a36","a37","a38","a39","a40","a41","a42","a43","a44","a45","a46","a47", \
 "a48","a49","a50","a51","a52","a53","a54","a55","a56","a57","a58","a59","a60","a61","a62","a63", \
 "a64","a65","a66","a67","a68","a69","a70","a71","a72","a73","a74","a75","a76","a77","a78","a79", \
 "a80","a81","a82","a83","a84","a85","a86","a87","a88","a89","a90","a91","a92","a93","a94","a95", \
 "a96","a97","a98","a99","a100","a101","a102","a103","a104","a105","a106","a107","a108","a109","a110","a111", \
 "a112","a113","a114","a115","a116","a117","a118","a119","a120","a121","a122","a123","a124","a125","a126","a127", \
 "a128","a129","a130","a131","a132","a133","a134","a135","a136","a137","a138","a139","a140","a141","a142","a143", \
 "a144","a145","a146","a147","a148","a149","a150","a151","a152","a153","a154","a155","a156","a157","a158","a159", \
 "a160","a161","a162","a163","a164","a165","a166","a167","a168","a169","a170","a171","a172","a173","a174","a175", \
 "a176","a177","a178","a179","a180","a181","a182","a183","a184","a185","a186","a187","a188","a189","a190","a191"

#define AFENCE asm volatile("" ::: ACLB)

#define BINIT8(G,S,KT,A0,A1,A2,A3,A4,A5,A6,A7) { \
  const u8* p = rkd + ((size_t)((G)*256 + w*64 + (S)*16 + lc)<<8) + (KT)*128 + quad*32; \
  i4v t0 = *(const i4v*)p; \
  i4v t1 = *(const i4v*)(p+16); \
  asm volatile("v_accvgpr_write_b32 a" #A0 ", %0\n\t" \
               "v_accvgpr_write_b32 a" #A1 ", %1\n\t" \
               "v_accvgpr_write_b32 a" #A2 ", %2\n\t" \
               "v_accvgpr_write_b32 a" #A3 ", %3\n\t" \
               "v_accvgpr_write_b32 a" #A4 ", %4\n\t" \
               "v_accvgpr_write_b32 a" #A5 ", %5\n\t" \
               "v_accvgpr_write_b32 a" #A6 ", %6\n\t" \
               "v_accvgpr_write_b32 a" #A7 ", %7" \
               :: "v"(t0[0]),"v"(t0[1]),"v"(t0[2]),"v"(t0[3]), \
                  "v"(t1[0]),"v"(t1[1]),"v"(t1[2]),"v"(t1[3]) : ACLB); }

// fp8 K=128 MFMA, B from AGPR (cbsz/blgp default 0 = e4m3 both operands)
#define MFZ8(ACC,AF,AR) \
  asm("v_mfma_f32_16x16x128_f8f6f4 %0, %1, " AR ", 0" : "=&v"(ACC) : "v"(AF))
#define MFA8(ACC,AF,AR) \
  asm("v_mfma_f32_16x16x128_f8f6f4 %0, %1, " AR ", %0" : "+v"(ACC) : "v"(AF))

// MFMA->VALU hazard fence: orders all acc reads after 16 nop cycles
#define FENCE12 asm volatile("s_nop 7\n\ts_nop 7" \
  : "+v"(acc[0]),"+v"(acc[1]),"+v"(acc[2]),"+v"(acc[3]), \
    "+v"(acc[4]),"+v"(acc[5]),"+v"(acc[6]),"+v"(acc[7]), \
    "+v"(acc[8]),"+v"(acc[9]),"+v"(acc[10]),"+v"(acc[11]) :: ACLB)

#define LBAR asm volatile("s_waitcnt lgkmcnt(0)\n\ts_barrier" ::: ACLB, "memory")

__device__ __forceinline__ float bsel(u32x2 v, int i){
  u32 wv = (i & 2) ? (u32)v[1] : (u32)v[0];
  return __uint_as_float((i & 1) ? (wv & 0xffff0000u) : (wv << 16));
}

// gate + state update for one ut (cell = acc[.][0]; batch = quad).
// Preacts in log2 domain: sigmoid(x)=rcp(1+2^(-xs)), tanh via 2^(hc_scaled).
// Raw v_exp_f32 (D=2^S0); -src modifier is free (VOP3).
#define GATE(UT) { \
  float xz = bsel(cz, UT); \
  float xr = bsel(cr, UT); \
  float xh = bsel(ch, UT); \
  float zf = acc[UT][0]   + xz; \
  float rf = acc[4+UT][0] + xr; \
  float rh = acc[8+UT][0] + b1h[UT]; \
  float ez, er, e2; \
  asm("v_exp_f32 %0, -%1" : "=v"(ez) : "v"(zf)); \
  asm("v_exp_f32 %0, -%1" : "=v"(er) : "v"(rf)); \
  zf = __builtin_amdgcn_rcpf(1.f + ez); \
  rf = __builtin_amdgcn_rcpf(1.f + er); \
  float hc = xh + rf*rh; \
  asm("v_exp_f32 %0, %1" : "=v"(e2) : "v"(hc)); \
  float th = 1.f - 2.f*__builtin_amdgcn_rcpf(e2 + 1.f); \
  float hn = th + zf*(hpc[UT] - th); \
  hpc[UT] = hn; \
  u32 q8; asm("v_cvt_pk_fp8_f32 %0, %1, %2" : "=v"(q8) : "v"(hn), "v"(hn)); \
  hb8[nxt][quad*4][w*64 + (UT)*16 + lc] = (u8)(q8 & 0xffu); \
  if(MODE == 0) \
    hp[(UT)*16] = f2bf(hn); \
}

template<int MODE>
__global__ __launch_bounds__(256,1) void gru_scan3(
    const u16* __restrict__ xq,    // packed preacts (see gemm_bt)
    const u8*  __restrict__ rkq,   // [2][768][256] fp8 transposed recurrent kernels
    const float* __restrict__ bF, const float* __restrict__ bB,  // b[2][768] f32
    u16* __restrict__ h1out,       // MODE 0: [BT,512]
    float* __restrict__ h2out)     // MODE 1: [64,512] final states
{
  int dir = blockIdx.x & 1, bg = blockIdx.x >> 1;
  int b0 = bg*4;
  int tid = threadIdx.x;
  int w = tid>>6, l = tid&63, lc = l&15, quad = l>>4;

  __shared__ u8 hb8[2][16][272];   // double-buffered h (fp8), rows {0,4,8,12} real
  for(int i=tid; i<2*16*272; i+=256) ((u8*)hb8)[i] = 0;

  const u8* rkd = rkq + (size_t)dir*G3*U_DIM;

  // B-frags: frag(g,s,kt) -> a[((g*4+s)*2+kt)*8 .. +7]
  BINIT8(0,0,0,  0,1,2,3,4,5,6,7)        BINIT8(0,0,1,  8,9,10,11,12,13,14,15)
  BINIT8(0,1,0, 16,17,18,19,20,21,22,23) BINIT8(0,1,1, 24,25,26,27,28,29,30,31)
  BINIT8(0,2,0, 32,33,34,35,36,37,38,39) BINIT8(0,2,1, 40,41,42,43,44,45,46,47)
  BINIT8(0,3,0, 48,49,50,51,52,53,54,55) BINIT8(0,3,1, 56,57,58,59,60,61,62,63)
  BINIT8(1,0,0, 64,65,66,67,68,69,70,71) BINIT8(1,0,1, 72,73,74,75,76,77,78,79)
  BINIT8(1,1,0, 80,81,82,83,84,85,86,87) BINIT8(1,1,1, 88,89,90,91,92,93,94,95)
  BINIT8(1,2,0, 96,97,98,99,100,101,102,103) BINIT8(1,2,1, 104,105,106,107,108,109,110,111)
  BINIT8(1,3,0, 112,113,114,115,116,117,118,119) BINIT8(1,3,1, 120,121,122,123,124,125,126,127)
  BINIT8(2,0,0, 128,129,130,131,132,133,134,135) BINIT8(2,0,1, 136,137,138,139,140,141,142,143)
  BINIT8(2,1,0, 144,145,146,147,148,149,150,151) BINIT8(2,1,1, 152,153,154,155,156,157,158,159)
  BINIT8(2,2,0, 160,161,162,163,164,165,166,167) BINIT8(2,2,1, 168,169,170,171,172,173,174,175)
  BINIT8(2,3,0, 176,177,178,179,180,181,182,183) BINIT8(2,3,1, 184,185,186,187,188,189,190,191)

  // recurrent bias for h-gate only (z,r folded into gemm bias); log2-scaled
  float b1h[4];
  const float* bias1 = (dir ? bB : bF) + G3;
  #pragma unroll
  for(int ut=0; ut<4; ut++) b1h[ut] = bias1[2*U_DIM + w*64 + ut*16 + lc] * L2E2;

  int t0 = dir ? (T_LEN-1) : 0;
  long qstride = dir ? -(long)(64*3*256) : (long)(64*3*256);
  const u16* xp = xq + ((((size_t)dir*T_LEN + t0)*B_SZ + (b0+quad))*3)*256 + lc*16 + w*4;
  long hstride = dir ? -(long)(2*U_DIM) : (long)(2*U_DIM);
  u16* hp = (MODE==0)
    ? (h1out + ((size_t)(b0+quad)*T_LEN + t0)*(2*U_DIM) + dir*U_DIM + w*64 + lc)
    : nullptr;

  float hpc[4] = {0.f, 0.f, 0.f, 0.f};   // carried h (own cells), f32

  // prologue load for step 0 (pipelined: consumed this step, next prefetched)
  u32x2 cz = *(const u32x2*)(xp);
  u32x2 cr = *(const u32x2*)(xp + 256);
  u32x2 ch = *(const u32x2*)(xp + 512);

  __syncthreads();

  int cur = 0;
  for(int step=0; step<T_LEN; step++){
    AFENCE;
    int nxt = cur ^ 1;

    // A-frags: h fp8, 32 B per lane per K-tile (row lc, k = quad*32..+31)
    i8v af0, af1;
    {
      const u8* p = &hb8[cur][lc][quad*32];
      i4v lo0 = *(const i4v*)p,        hi0 = *(const i4v*)(p+16);
      i4v lo1 = *(const i4v*)(p+128),  hi1 = *(const i4v*)(p+144);
      af0 = __builtin_shufflevector(lo0, hi0, 0,1,2,3,4,5,6,7);
      af1 = __builtin_shufflevector(lo1, hi1, 0,1,2,3,4,5,6,7);
    }

    // prefetch next step's preacts (t=±512 lands in the other dir's region:
    // valid memory, values unused) — ~1 full step of latency cover
    const u16* xpn = xp + qstride;
    u32x2 czn = *(const u32x2*)(xpn);
    u32x2 crn = *(const u32x2*)(xpn + 256);
    u32x2 chn = *(const u32x2*)(xpn + 512);

    f4v acc[12];   // [g*4+ut]; cell value in reg 0 (batch = quad at row quad*4)
    // K-tile 0
    MFZ8(acc[0], af0,"a[0:7]");     MFZ8(acc[1], af0,"a[16:23]");
    MFZ8(acc[2], af0,"a[32:39]");   MFZ8(acc[3], af0,"a[48:55]");
    MFZ8(acc[4], af0,"a[64:71]");   MFZ8(acc[5], af0,"a[80:87]");
    MFZ8(acc[6], af0,"a[96:103]");  MFZ8(acc[7], af0,"a[112:119]");
    MFZ8(acc[8], af0,"a[128:135]"); MFZ8(acc[9], af0,"a[144:151]");
    MFZ8(acc[10],af0,"a[160:167]"); MFZ8(acc[11],af0,"a[176:183]");
    // K-tile 1
    MFA8(acc[0], af1,"a[8:15]");    MFA8(acc[1], af1,"a[24:31]");
    MFA8(acc[2], af1,"a[40:47]");   MFA8(acc[3], af1,"a[56:63]");
    MFA8(acc[4], af1,"a[72:79]");   MFA8(acc[5], af1,"a[88:95]");
    MFA8(acc[6], af1,"a[104:111]"); MFA8(acc[7], af1,"a[120:127]");
    MFA8(acc[8], af1,"a[136:143]"); MFA8(acc[9], af1,"a[152:159]");
    MFA8(acc[10],af1,"a[168:175]"); MFA8(acc[11],af1,"a[184:191]");
    FENCE12;

    GATE(0)
    GATE(1)
    GATE(2)
    GATE(3)

    cz = czn; cr = crn; ch = chn;
    xp = xpn;
    if(MODE==0) hp += hstride;
    LBAR;
    cur ^= 1;
  }

  // epilogue: MODE 1 final states from carried registers
  if(MODE==1){
    #pragma unroll
    for(int ut=0;ut<4;ut++)
      h2out[(size_t)(b0+quad)*(2*U_DIM) + dir*U_DIM + w*64 + ut*16 + lc] = hpc[ut];
  }
}

// ---------------- final projection + softmax (f32 output) ---------------------
__global__ void out_softmax(const float* __restrict__ h2, const float* __restrict__ wout,
                            const float* __restrict__ bout, float* __restrict__ out)
{
  __shared__ float lg[C_DIM];
  int b = blockIdx.x, l = threadIdx.x;   // 64 threads = 1 wave
  float acc[C_DIM];
  #pragma unroll
  for(int c=0;c<C_DIM;c++) acc[c] = 0.f;
  for(int k=l; k<2*U_DIM; k+=64){
    float hv = h2[b*2*U_DIM + k];
    #pragma unroll
    for(int c=0;c<C_DIM;c++) acc[c] += hv * wout[k*C_DIM + c];
  }
  #pragma unroll
  for(int c=0;c<C_DIM;c++){
    float v = acc[c];
    for(int off=32; off; off>>=1) v += __shfl_down(v, off);
    if(l==0) lg[c] = v + bout[c];
  }
  __syncthreads();
  if(l==0){
    float mx = lg[0];
    for(int c=1;c<C_DIM;c++) mx = fmaxf(mx, lg[c]);
    float sum = 0.f, ex[C_DIM];
    for(int c=0;c<C_DIM;c++){ ex[c] = __expf(lg[c]-mx); sum += ex[c]; }
    for(int c=0;c<C_DIM;c++) out[b*C_DIM + c] = ex[c]/sum;
  }
}

extern "C" void kernel_launch(void* const* d_in, const int* in_sizes, int n_in,
                              void* d_out, int out_size, void* d_ws, size_t ws_size,
                              hipStream_t stream)
{
  const int*   x    = (const int*)d_in[0];
  const float* emb  = (const float*)d_in[1];
  const float* k1f  = (const float*)d_in[2];
  const float* rk1f = (const float*)d_in[3];
  const float* b1f  = (const float*)d_in[4];
  const float* k1b  = (const float*)d_in[5];
  const float* rk1b = (const float*)d_in[6];
  const float* b1b  = (const float*)d_in[7];
  const float* k2f  = (const float*)d_in[8];
  const float* rk2f = (const float*)d_in[9];
  const float* b2f  = (const float*)d_in[10];
  const float* k2b  = (const float*)d_in[11];
  const float* rk2b = (const float*)d_in[12];
  const float* b2b  = (const float*)d_in[13];
  const float* wout = (const float*)d_in[14];
  const float* bout = (const float*)d_in[15];

  char* ws = (char*)d_ws;
  u16*  k1t   = (u16*)(ws);                       // 983,040 B     [1536,320]
  u16*  k2t   = (u16*)(ws + 983040);              // 1,572,864 B   [1536,512]
  u8*   rkq   = (u8*)(ws + 2555904);              // 786,432 B     4x[768,256] fp8
  float* h2   = (float*)(ws + 4128768);           // 131,072 B     [64,512]
  u16*  h1    = (u16*)(ws + 4259840);             // 33,554,432 B  [BT,512]
  u16*  e_pad = (u16*)(ws + 4259840);             // (alias h1)
  u16*  xq    = (u16*)(ws + 37814272);            // 100,663,296 B packed preacts

  transpose_cc<<<(NTOT*EP +255)/256,256,0,stream>>>(k1f, k1b, k1t, E_DIM, EP, NTOT);
  transpose_cc<<<(NTOT*512+255)/256,256,0,stream>>>(k2f, k2b, k2t, 512, 512, NTOT);
  transpose_fp8<<<768,256,0,stream>>>(rk1f, rkq);
  transpose_fp8<<<768,256,0,stream>>>(rk1b, rkq + 1*G3*U_DIM);
  transpose_fp8<<<768,256,0,stream>>>(rk2f, rkq + 2*G3*U_DIM);
  transpose_fp8<<<768,256,0,stream>>>(rk2b, rkq + 3*G3*U_DIM);

  embed_pad<<<(BT*EP)/256,256,0,stream>>>(x, emb, e_pad);

  // layer 1: xq = pack((e @ K1 + b0 [+ b1 for z,r]) * log2e-scale) ; scan -> h1
  gemm_bt<<<dim3(12,256),256,0,stream>>>(e_pad, k1t, xq, EP, b1f, b1b);
  gru_scan3<0><<<32,256,0,stream>>>(xq, rkq, b1f, b1b, h1, nullptr);

  // layer 2: same pipeline ; scan -> h2 (final states only)
  gemm_bt<<<dim3(12,256),256,0,stream>>>(h1, k2t, xq, 512, b2f, b2b);
  gru_scan3<1><<<32,256,0,stream>>>(xq, rkq + 2*G3*U_DIM, b2f, b2b, nullptr, h2);

  out_softmax<<<64,64,0,stream>>>(h2, wout, bout, (float*)d_out);
}

// Round 12
// 1088.894 us; speedup vs baseline: 1.1016x; 1.0114x over previous
//
#include <hip/hip_runtime.h>

typedef unsigned char  u8;
typedef unsigned short u16;
typedef unsigned int   u32;
typedef unsigned long long u64;
typedef __attribute__((ext_vector_type(8))) short s8v;   // 8 x bf16 bits (4 VGPRs)
typedef __attribute__((ext_vector_type(4))) float f4v;   // MFMA accumulator
typedef __attribute__((ext_vector_type(4))) int   i4v;   // 4 VGPRs (generic 16B)
typedef __attribute__((ext_vector_type(8))) int   i8v;   // 8 VGPRs (fp8 MFMA operand)
typedef __attribute__((ext_vector_type(2))) unsigned int u32x2;

#define B_SZ  64
#define T_LEN 512
#define U_DIM 256
#define E_DIM 300
#define EP    320          // E padded to multiple of 32
#define G3    768          // 3*U
#define NTOT  1536         // both directions concatenated
#define C_DIM 20
#define BT    (B_SZ*T_LEN)

// log2(e) scales folded into weights/biases so gates use a single v_exp_f32
#define L2E  1.44269504088896f
#define L2E2 2.88539008177793f

__device__ __forceinline__ float bf2f(u16 h){ return __uint_as_float(((u32)h)<<16); }
__device__ __forceinline__ u16 f2bf(float f){
  u32 u = __float_as_uint(f);
  u32 r = (u + 0x7FFFu + ((u>>16)&1u)) >> 16;   // RNE
  return (u16)r;
}

// f32 -> OCP e4m3fn, RNE, handles subnormals + 448 clamp (prep kernel only)
__device__ __forceinline__ u8 f2fp8(float f){
  u32 u = __float_as_uint(f);
  u32 s = (u>>24)&0x80u;
  u32 au = u & 0x7fffffffu;
  if(au < 0x3C800000u){                       // |f| < 2^-6: subnormal range
    float m = rintf(__uint_as_float(au) * 512.f);   // 0..8 (RNE)
    return (u8)(s | (u32)(int)m);             // m==8 -> 0x08 == 2^-6 normal
  }
  int e = (int)(au>>23) - 127;
  u32 mant = au & 0x7fffffu;
  u32 lsb = (mant>>20)&1u;
  mant += 0x7FFFFu + lsb;                     // RNE to 3 mantissa bits
  if(mant >> 23){ mant = 0; e += 1; }
  if(e > 8 || (e==8 && ((mant>>20)&7u)==7u)) return (u8)(s | 0x7Eu);  // clamp 448
  return (u8)(s | ((u32)(e+7)<<3) | ((mant>>20)&7u));
}

// ------------- fused prep: embedding + all weight transposes (1 launch) -------
// Section boundaries (all multiples of 256 threads/block, no remainders):
//   [0,40960)        embed gather f32->bf16, K-pad 300->320
//   [40960,42880)    k1t  transpose+concat [1536,320] bf16 (log2e-scaled)
//   [42880,45952)    k2t  transpose+concat [1536,512] bf16 (log2e-scaled)
//   [45952,49024)    rkq  fp8 transposes, 4 x [768,256]   (log2e-scaled)
#define PB0 40960
#define PB1 42880
#define PB2 45952
#define PB3 49024

__global__ __launch_bounds__(256) void prep_all(
    const int* __restrict__ x, const float* __restrict__ emb, u16* __restrict__ e,
    const float* __restrict__ k1f, const float* __restrict__ k1b, u16* __restrict__ k1t,
    const float* __restrict__ k2f, const float* __restrict__ k2b, u16* __restrict__ k2t,
    const float* __restrict__ rk1f, const float* __restrict__ rk1b,
    const float* __restrict__ rk2f, const float* __restrict__ rk2b,
    u8* __restrict__ rkq)
{
  int bid = blockIdx.x, tid = threadIdx.x;
  if(bid < PB0){
    int idx = bid*256 + tid;                       // BT*EP
    int row = idx / EP, col = idx - row*EP;
    u16 v = 0;
    if(col < E_DIM) v = f2bf(emb[(size_t)x[row]*E_DIM + col]);
    e[idx] = v;
  } else if(bid < PB1){
    int idx = (bid-PB0)*256 + tid;                 // NTOT*EP
    int n = idx / EP, k = idx - n*EP;
    u16 v = 0;
    if(k < E_DIM){
      const float* s = (n < G3) ? k1f : k1b;
      int nn = (n < G3) ? n : n - G3;
      float sc = ((nn>>8)==2) ? L2E2 : L2E;
      v = f2bf(s[(size_t)k*G3 + nn] * sc);
    }
    k1t[idx] = v;
  } else if(bid < PB2){
    int idx = (bid-PB1)*256 + tid;                 // NTOT*512
    int n = idx >> 9, k = idx & 511;
    const float* s = (n < G3) ? k2f : k2b;
    int nn = (n < G3) ? n : n - G3;
    float sc = ((nn>>8)==2) ? L2E2 : L2E;
    k2t[idx] = f2bf(s[(size_t)k*G3 + nn] * sc);
  } else {
    int idx4 = (bid-PB2)*256 + tid;                // 4 * G3*U_DIM
    int m = idx4 / (G3*U_DIM), idx = idx4 - m*(G3*U_DIM);
    const float* rk = (m==0) ? rk1f : (m==1) ? rk1b : (m==2) ? rk2f : rk2b;
    int n = idx >> 8, k = idx & 255;
    float sc = ((n>>8)==2) ? L2E2 : L2E;
    rkq[idx4] = f2fp8(rk[(size_t)k*G3 + n] * sc);
  }
}

// ------- GEMM: packed preacts for the M=4 scan -------------------------------
// xq layout (u16): [dir][t][b][g][lc16][ut16]; total 2*512*64*3*256 u16.
// Double-buffered LDS pipeline, ONE barrier per K-step (R11).
__global__ __launch_bounds__(256) void gemm_bt(
    const u16* __restrict__ A, const u16* __restrict__ BT_, u16* __restrict__ Cq,
    int Kp, const float* __restrict__ biasA, const float* __restrict__ biasB)
{
  __shared__ u16 Al[2][128][40];   // +8 pad breaks bank collisions
  __shared__ u16 Bl[2][128][40];
  int tid = threadIdx.x;
  int w = tid>>6, l = tid&63, lc = l&15, quad = l>>4;
  int wm = w>>1, wn = w&1;
  int nb = blockIdx.x*128;
  int bg4 = blockIdx.y >> 4, tg = blockIdx.y & 15;
  int b0r = bg4*4, tb0 = tg*32;

  f4v acc[4][4];
  #pragma unroll
  for(int i=0;i<4;i++)
    #pragma unroll
    for(int j=0;j<4;j++) acc[i][j] = (f4v){0.f,0.f,0.f,0.f};

  // staging geometry: thread -> (row r0 & r0+64, 8-elem k-block k8)
  int r0 = tid>>2, k8 = tid&3;
  int r1 = r0 + 64;
  const u16* pa0 = A + ((size_t)(b0r + (r0&3))*T_LEN + tb0 + (r0>>2))*Kp + k8*8;
  const u16* pa1 = A + ((size_t)(b0r + (r1&3))*T_LEN + tb0 + (r1>>2))*Kp + k8*8;
  const u16* pb0 = BT_ + (size_t)(nb+r0)*Kp + k8*8;
  const u16* pb1 = BT_ + (size_t)(nb+r1)*Kp + k8*8;

  // prologue: K-tile 0 into registers
  s8v ra0 = *(const s8v*)pa0, ra1 = *(const s8v*)pa1;
  s8v rb0 = *(const s8v*)pb0, rb1 = *(const s8v*)pb1;

  int nk = Kp >> 5;
  int cur = 0;
  for(int kt=0; kt<nk; kt++){
    *(s8v*)&Al[cur][r0][k8*8] = ra0;
    *(s8v*)&Al[cur][r1][k8*8] = ra1;
    *(s8v*)&Bl[cur][r0][k8*8] = rb0;
    *(s8v*)&Bl[cur][r1][k8*8] = rb1;
    __syncthreads();
    if(kt+1 < nk){
      int off = (kt+1)*32;
      ra0 = *(const s8v*)(pa0 + off);
      ra1 = *(const s8v*)(pa1 + off);
      rb0 = *(const s8v*)(pb0 + off);
      rb1 = *(const s8v*)(pb1 + off);
    }
    s8v af[4], bf[4];
    #pragma unroll
    for(int i=0;i<4;i++) af[i] = *(const s8v*)&Al[cur][wm*64 + i*16 + lc][quad*8];
    #pragma unroll
    for(int j=0;j<4;j++) bf[j] = *(const s8v*)&Bl[cur][wn*64 + j*16 + lc][quad*8];
    #pragma unroll
    for(int i=0;i<4;i++)
      #pragma unroll
      for(int j=0;j<4;j++)
        acc[i][j] = __builtin_amdgcn_mfma_f32_16x16x32_bf16(af[i], bf[j], acc[i][j],0,0,0);
    cur ^= 1;
  }

  // packed epilogue -> xq[dir][t][b][g][lc][ut], one u64 (4 ut) per (i,r)
  int dirq = (nb >= G3) ? 1 : 0;
  int c7b  = nb - dirq*G3 + wn*64;      // col within dir, minus lc and j*16
  int g    = c7b >> 8;
  int ut0  = (c7b >> 4) & 15;
  const float* bb = dirq ? biasB : biasA;
  float gsc = (g < 2) ? L2E : L2E2;
  float bj[4];
  #pragma unroll
  for(int j=0;j<4;j++){
    int cc = c7b + j*16 + lc;
    bj[j] = (bb[cc] + ((g < 2) ? bb[G3 + cc] : 0.f)) * gsc;  // fold b[1] for z,r
  }
  #pragma unroll
  for(int i=0;i<4;i++){
    int t = tb0 + wm*16 + i*4 + quad;
    size_t base = ((((size_t)dirq*T_LEN + t)*B_SZ + b0r)*3 + g)*256 + lc*16 + ut0;
    #pragma unroll
    for(int r=0;r<4;r++){
      u16 p0 = f2bf(acc[i][0][r] + bj[0]);
      u16 p1 = f2bf(acc[i][1][r] + bj[1]);
      u16 p2 = f2bf(acc[i][2][r] + bj[2]);
      u16 p3 = f2bf(acc[i][3][r] + bj[3]);
      *(u64*)(Cq + base + (size_t)r*768) =
        (u64)p0 | ((u64)p1<<16) | ((u64)p2<<32) | ((u64)p3<<48);
    }
  }
}

// ---------------- GRU scan: fp8 K=128 MFMA, register-resident weights --------
// 32 blocks (dir x 16 batch-groups of 4) x 256 threads (4 waves, 1 wave/SIMD).
// Per wave: 192 N-cols (3 gates x 64 u) x K=256 fp8 -> 24 B-frags x 8 AGPRs =
// a0..a191. h exchanged per step via LDS as fp8 bytes; gate state in f32.
// 24 MFMAs/step/wave (12 N-tiles x 2 K-tiles of 16x16x128).
// xq preact loads pipelined one step ahead. Preacts/weights pre-scaled by
// log2e (z,r) / 2*log2e (h); gates use raw v_exp_f32 (R9 lesson: OCML exp2f
// adds guard code).

#define ACLB \
 "a0","a1","a2","a3","a4","a5","a6","a7","a8","a9","a10","a11","a12","a13","a14","a15", \
 "a16","a17","a18","a19","a20","a21","a22","a23","a24","a25","a26","a27","a28","a29","a30","a31", \
 "a32","a33","a34","a35","a36","a37","a38","a39","a40","a41","a42","a43","a44","a45","a46","a47", \
 "a48","a49","a50","a51","a52","a53","a54","a55","a56","a57","a58","a59","a60","a61","a62","a63", \
 "a64","a65","a66","a67","a68","a69","a70","a71","a72","a73","a74","a75","a76","a77","a78","a79", \
 "a80","a81","a82","a83","a84","a85","a86","a87","a88","a89","a90","a91","a92","a93","a94","a95", \
 "a96","a97","a98","a99","a100","a101","a102","a103","a104","a105","a106","a107","a108","a109","a110","a111", \
 "a112","a113","a114","a115","a116","a117","a118","a119","a120","a121","a122","a123","a124","a125","a126","a127", \
 "a128","a129","a130","a131","a132","a133","a134","a135","a136","a137","a138","a139","a140","a141","a142","a143", \
 "a144","a145","a146","a147","a148","a149","a150","a151","a152","a153","a154","a155","a156","a157","a158","a159", \
 "a160","a161","a162","a163","a164","a165","a166","a167","a168","a169","a170","a171","a172","a173","a174","a175", \
 "a176","a177","a178","a179","a180","a181","a182","a183","a184","a185","a186","a187","a188","a189","a190","a191"

#define AFENCE asm volatile("" ::: ACLB)

#define BINIT8(G,S,KT,A0,A1,A2,A3,A4,A5,A6,A7) { \
  const u8* p = rkd + ((size_t)((G)*256 + w*64 + (S)*16 + lc)<<8) + (KT)*128 + quad*32; \
  i4v t0 = *(const i4v*)p; \
  i4v t1 = *(const i4v*)(p+16); \
  asm volatile("v_accvgpr_write_b32 a" #A0 ", %0\n\t" \
               "v_accvgpr_write_b32 a" #A1 ", %1\n\t" \
               "v_accvgpr_write_b32 a" #A2 ", %2\n\t" \
               "v_accvgpr_write_b32 a" #A3 ", %3\n\t" \
               "v_accvgpr_write_b32 a" #A4 ", %4\n\t" \
               "v_accvgpr_write_b32 a" #A5 ", %5\n\t" \
               "v_accvgpr_write_b32 a" #A6 ", %6\n\t" \
               "v_accvgpr_write_b32 a" #A7 ", %7" \
               :: "v"(t0[0]),"v"(t0[1]),"v"(t0[2]),"v"(t0[3]), \
                  "v"(t1[0]),"v"(t1[1]),"v"(t1[2]),"v"(t1[3]) : ACLB); }

// fp8 K=128 MFMA, B from AGPR (cbsz/blgp default 0 = e4m3 both operands)
#define MFZ8(ACC,AF,AR) \
  asm("v_mfma_f32_16x16x128_f8f6f4 %0, %1, " AR ", 0" : "=&v"(ACC) : "v"(AF))
#define MFA8(ACC,AF,AR) \
  asm("v_mfma_f32_16x16x128_f8f6f4 %0, %1, " AR ", %0" : "+v"(ACC) : "v"(AF))

// MFMA->VALU hazard fence: orders all acc reads after 16 nop cycles
#define FENCE12 asm volatile("s_nop 7\n\ts_nop 7" \
  : "+v"(acc[0]),"+v"(acc[1]),"+v"(acc[2]),"+v"(acc[3]), \
    "+v"(acc[4]),"+v"(acc[5]),"+v"(acc[6]),"+v"(acc[7]), \
    "+v"(acc[8]),"+v"(acc[9]),"+v"(acc[10]),"+v"(acc[11]) :: ACLB)

#define LBAR asm volatile("s_waitcnt lgkmcnt(0)\n\ts_barrier" ::: ACLB, "memory")

__device__ __forceinline__ float bsel(u32x2 v, int i){
  u32 wv = (i & 2) ? (u32)v[1] : (u32)v[0];
  return __uint_as_float((i & 1) ? (wv & 0xffff0000u) : (wv << 16));
}

// gate + state update for one ut (cell = acc[.][0]; batch = quad).
// Preacts in log2 domain: sigmoid(x)=rcp(1+2^(-xs)), tanh via 2^(hc_scaled).
// Raw v_exp_f32 (D=2^S0); -src modifier is free (VOP3).
#define GATE(UT) { \
  float xz = bsel(cz, UT); \
  float xr = bsel(cr, UT); \
  float xh = bsel(ch, UT); \
  float zf = acc[UT][0]   + xz; \
  float rf = acc[4+UT][0] + xr; \
  float rh = acc[8+UT][0] + b1h[UT]; \
  float ez, er, e2; \
  asm("v_exp_f32 %0, -%1" : "=v"(ez) : "v"(zf)); \
  asm("v_exp_f32 %0, -%1" : "=v"(er) : "v"(rf)); \
  zf = __builtin_amdgcn_rcpf(1.f + ez); \
  rf = __builtin_amdgcn_rcpf(1.f + er); \
  float hc = xh + rf*rh; \
  asm("v_exp_f32 %0, %1" : "=v"(e2) : "v"(hc)); \
  float th = 1.f - 2.f*__builtin_amdgcn_rcpf(e2 + 1.f); \
  float hn = th + zf*(hpc[UT] - th); \
  hpc[UT] = hn; \
  u32 q8; asm("v_cvt_pk_fp8_f32 %0, %1, %2" : "=v"(q8) : "v"(hn), "v"(hn)); \
  hb8[nxt][quad*4][w*64 + (UT)*16 + lc] = (u8)(q8 & 0xffu); \
  if(MODE == 0) \
    hp[(UT)*16] = f2bf(hn); \
}

template<int MODE>
__global__ __launch_bounds__(256,1) void gru_scan3(
    const u16* __restrict__ xq,    // packed preacts (see gemm_bt)
    const u8*  __restrict__ rkq,   // [2][768][256] fp8 transposed recurrent kernels
    const float* __restrict__ bF, const float* __restrict__ bB,  // b[2][768] f32
    u16* __restrict__ h1out,       // MODE 0: [BT,512]
    float* __restrict__ h2out)     // MODE 1: [64,512] final states
{
  int dir = blockIdx.x & 1, bg = blockIdx.x >> 1;
  int b0 = bg*4;
  int tid = threadIdx.x;
  int w = tid>>6, l = tid&63, lc = l&15, quad = l>>4;

  __shared__ u8 hb8[2][16][272];   // double-buffered h (fp8), rows {0,4,8,12} real
  for(int i=tid; i<2*16*272; i+=256) ((u8*)hb8)[i] = 0;

  const u8* rkd = rkq + (size_t)dir*G3*U_DIM;

  // B-frags: frag(g,s,kt) -> a[((g*4+s)*2+kt)*8 .. +7]
  BINIT8(0,0,0,  0,1,2,3,4,5,6,7)        BINIT8(0,0,1,  8,9,10,11,12,13,14,15)
  BINIT8(0,1,0, 16,17,18,19,20,21,22,23) BINIT8(0,1,1, 24,25,26,27,28,29,30,31)
  BINIT8(0,2,0, 32,33,34,35,36,37,38,39) BINIT8(0,2,1, 40,41,42,43,44,45,46,47)
  BINIT8(0,3,0, 48,49,50,51,52,53,54,55) BINIT8(0,3,1, 56,57,58,59,60,61,62,63)
  BINIT8(1,0,0, 64,65,66,67,68,69,70,71) BINIT8(1,0,1, 72,73,74,75,76,77,78,79)
  BINIT8(1,1,0, 80,81,82,83,84,85,86,87) BINIT8(1,1,1, 88,89,90,91,92,93,94,95)
  BINIT8(1,2,0, 96,97,98,99,100,101,102,103) BINIT8(1,2,1, 104,105,106,107,108,109,110,111)
  BINIT8(1,3,0, 112,113,114,115,116,117,118,119) BINIT8(1,3,1, 120,121,122,123,124,125,126,127)
  BINIT8(2,0,0, 128,129,130,131,132,133,134,135) BINIT8(2,0,1, 136,137,138,139,140,141,142,143)
  BINIT8(2,1,0, 144,145,146,147,148,149,150,151) BINIT8(2,1,1, 152,153,154,155,156,157,158,159)
  BINIT8(2,2,0, 160,161,162,163,164,165,166,167) BINIT8(2,2,1, 168,169,170,171,172,173,174,175)
  BINIT8(2,3,0, 176,177,178,179,180,181,182,183) BINIT8(2,3,1, 184,185,186,187,188,189,190,191)

  // recurrent bias for h-gate only (z,r folded into gemm bias); log2-scaled
  float b1h[4];
  const float* bias1 = (dir ? bB : bF) + G3;
  #pragma unroll
  for(int ut=0; ut<4; ut++) b1h[ut] = bias1[2*U_DIM + w*64 + ut*16 + lc] * L2E2;

  int t0 = dir ? (T_LEN-1) : 0;
  long qstride = dir ? -(long)(64*3*256) : (long)(64*3*256);
  const u16* xp = xq + ((((size_t)dir*T_LEN + t0)*B_SZ + (b0+quad))*3)*256 + lc*16 + w*4;
  long hstride = dir ? -(long)(2*U_DIM) : (long)(2*U_DIM);
  u16* hp = (MODE==0)
    ? (h1out + ((size_t)(b0+quad)*T_LEN + t0)*(2*U_DIM) + dir*U_DIM + w*64 + lc)
    : nullptr;

  float hpc[4] = {0.f, 0.f, 0.f, 0.f};   // carried h (own cells), f32

  // prologue load for step 0 (pipelined: consumed this step, next prefetched)
  u32x2 cz = *(const u32x2*)(xp);
  u32x2 cr = *(const u32x2*)(xp + 256);
  u32x2 ch = *(const u32x2*)(xp + 512);

  __syncthreads();

  int cur = 0;
  for(int step=0; step<T_LEN; step++){
    AFENCE;
    int nxt = cur ^ 1;

    // A-frags: h fp8, 32 B per lane per K-tile (row lc, k = quad*32..+31)
    i8v af0, af1;
    {
      const u8* p = &hb8[cur][lc][quad*32];
      i4v lo0 = *(const i4v*)p,        hi0 = *(const i4v*)(p+16);
      i4v lo1 = *(const i4v*)(p+128),  hi1 = *(const i4v*)(p+144);
      af0 = __builtin_shufflevector(lo0, hi0, 0,1,2,3,4,5,6,7);
      af1 = __builtin_shufflevector(lo1, hi1, 0,1,2,3,4,5,6,7);
    }

    // prefetch next step's preacts (t=±512 lands in the other dir's region:
    // valid memory, values unused) — ~1 full step of latency cover
    const u16* xpn = xp + qstride;
    u32x2 czn = *(const u32x2*)(xpn);
    u32x2 crn = *(const u32x2*)(xpn + 256);
    u32x2 chn = *(const u32x2*)(xpn + 512);

    f4v acc[12];   // [g*4+ut]; cell value in reg 0 (batch = quad at row quad*4)
    // K-tile 0
    MFZ8(acc[0], af0,"a[0:7]");     MFZ8(acc[1], af0,"a[16:23]");
    MFZ8(acc[2], af0,"a[32:39]");   MFZ8(acc[3], af0,"a[48:55]");
    MFZ8(acc[4], af0,"a[64:71]");   MFZ8(acc[5], af0,"a[80:87]");
    MFZ8(acc[6], af0,"a[96:103]");  MFZ8(acc[7], af0,"a[112:119]");
    MFZ8(acc[8], af0,"a[128:135]"); MFZ8(acc[9], af0,"a[144:151]");
    MFZ8(acc[10],af0,"a[160:167]"); MFZ8(acc[11],af0,"a[176:183]");
    // K-tile 1
    MFA8(acc[0], af1,"a[8:15]");    MFA8(acc[1], af1,"a[24:31]");
    MFA8(acc[2], af1,"a[40:47]");   MFA8(acc[3], af1,"a[56:63]");
    MFA8(acc[4], af1,"a[72:79]");   MFA8(acc[5], af1,"a[88:95]");
    MFA8(acc[6], af1,"a[104:111]"); MFA8(acc[7], af1,"a[120:127]");
    MFA8(acc[8], af1,"a[136:143]"); MFA8(acc[9], af1,"a[152:159]");
    MFA8(acc[10],af1,"a[168:175]"); MFA8(acc[11],af1,"a[184:191]");
    FENCE12;

    GATE(0)
    GATE(1)
    GATE(2)
    GATE(3)

    cz = czn; cr = crn; ch = chn;
    xp = xpn;
    if(MODE==0) hp += hstride;
    LBAR;
    cur ^= 1;
  }

  // epilogue: MODE 1 final states from carried registers
  if(MODE==1){
    #pragma unroll
    for(int ut=0;ut<4;ut++)
      h2out[(size_t)(b0+quad)*(2*U_DIM) + dir*U_DIM + w*64 + ut*16 + lc] = hpc[ut];
  }
}

// ---------------- final projection + softmax (f32 output) ---------------------
__global__ void out_softmax(const float* __restrict__ h2, const float* __restrict__ wout,
                            const float* __restrict__ bout, float* __restrict__ out)
{
  __shared__ float lg[C_DIM];
  int b = blockIdx.x, l = threadIdx.x;   // 64 threads = 1 wave
  float acc[C_DIM];
  #pragma unroll
  for(int c=0;c<C_DIM;c++) acc[c] = 0.f;
  for(int k=l; k<2*U_DIM; k+=64){
    float hv = h2[b*2*U_DIM + k];
    #pragma unroll
    for(int c=0;c<C_DIM;c++) acc[c] += hv * wout[k*C_DIM + c];
  }
  #pragma unroll
  for(int c=0;c<C_DIM;c++){
    float v = acc[c];
    for(int off=32; off; off>>=1) v += __shfl_down(v, off);
    if(l==0) lg[c] = v + bout[c];
  }
  __syncthreads();
  if(l==0){
    float mx = lg[0];
    for(int c=1;c<C_DIM;c++) mx = fmaxf(mx, lg[c]);
    float sum = 0.f, ex[C_DIM];
    for(int c=0;c<C_DIM;c++){ ex[c] = __expf(lg[c]-mx); sum += ex[c]; }
    for(int c=0;c<C_DIM;c++) out[b*C_DIM + c] = ex[c]/sum;
  }
}

extern "C" void kernel_launch(void* const* d_in, const int* in_sizes, int n_in,
                              void* d_out, int out_size, void* d_ws, size_t ws_size,
                              hipStream_t stream)
{
  const int*   x    = (const int*)d_in[0];
  const float* emb  = (const float*)d_in[1];
  const float* k1f  = (const float*)d_in[2];
  const float* rk1f = (const float*)d_in[3];
  const float* b1f  = (const float*)d_in[4];
  const float* k1b  = (const float*)d_in[5];
  const float* rk1b = (const float*)d_in[6];
  const float* b1b  = (const float*)d_in[7];
  const float* k2f  = (const float*)d_in[8];
  const float* rk2f = (const float*)d_in[9];
  const float* b2f  = (const float*)d_in[10];
  const float* k2b  = (const float*)d_in[11];
  const float* rk2b = (const float*)d_in[12];
  const float* b2b  = (const float*)d_in[13];
  const float* wout = (const float*)d_in[14];
  const float* bout = (const float*)d_in[15];

  char* ws = (char*)d_ws;
  u16*  k1t   = (u16*)(ws);                       // 983,040 B     [1536,320]
  u16*  k2t   = (u16*)(ws + 983040);              // 1,572,864 B   [1536,512]
  u8*   rkq   = (u8*)(ws + 2555904);              // 786,432 B     4x[768,256] fp8
  float* h2   = (float*)(ws + 4128768);           // 131,072 B     [64,512]
  u16*  h1    = (u16*)(ws + 4259840);             // 33,554,432 B  [BT,512]
  u16*  e_pad = (u16*)(ws + 4259840);             // (alias h1)
  u16*  xq    = (u16*)(ws + 37814272);            // 100,663,296 B packed preacts

  // one fused prep launch: embedding + all weight transposes
  prep_all<<<PB3,256,0,stream>>>(x, emb, e_pad,
                                 k1f, k1b, k1t,
                                 k2f, k2b, k2t,
                                 rk1f, rk1b, rk2f, rk2b, rkq);

  // layer 1: xq = pack((e @ K1 + b0 [+ b1 for z,r]) * log2e-scale) ; scan -> h1
  gemm_bt<<<dim3(12,256),256,0,stream>>>(e_pad, k1t, xq, EP, b1f, b1b);
  gru_scan3<0><<<32,256,0,stream>>>(xq, rkq, b1f, b1b, h1, nullptr);

  // layer 2: same pipeline ; scan -> h2 (final states only)
  gemm_bt<<<dim3(12,256),256,0,stream>>>(h1, k2t, xq, 512, b2f, b2b);
  gru_scan3<1><<<32,256,0,stream>>>(xq, rkq + 2*G3*U_DIM, b2f, b2b, nullptr, h2);

  out_softmax<<<64,64,0,stream>>>(h2, wout, bout, (float*)d_out);
}